// Round 10
// baseline (773.550 us; speedup 1.0000x reference)
//
#include <hip/hip_runtime.h>
#include <hip/hip_bf16.h>

#define B_ 4
#define P_ 12
#define Q_ 12
#define N_ 2048
#define D_ 32
#define ELLW 96

typedef __hip_bfloat16 bf16;

// Dual-path input load: flag==0 -> bf16 storage, flag==1 -> fp32 storage.
__device__ __forceinline__ float ld(const void* p, int i, int flag) {
    if (flag) return ((const float*)p)[i];
    unsigned int u = ((const unsigned short*)p)[i];
    return __uint_as_float(u << 16);
}

__device__ __forceinline__ float tf(float x) { return x; }
__device__ __forceinline__ float tf(bf16 x) { return __bfloat162float(x); }
__device__ __forceinline__ void ld4(const float* p, float4& v) { v = *(const float4*)p; }

#define GATHER8(SRC, D0, A)                                                            \
    {                                                                                  \
        int4 c0 = *(const int4*)(cols + i);                                            \
        int4 c1 = *(const int4*)(cols + i + 4);                                        \
        float4 v0 = *(const float4*)(vals + i);                                        \
        float4 v1 = *(const float4*)(vals + i + 4);                                    \
        float4 x;                                                                      \
        ld4(SRC + c0.x * 32 + D0, x); A.x += v0.x * x.x; A.y += v0.x * x.y; A.z += v0.x * x.z; A.w += v0.x * x.w; \
        ld4(SRC + c0.y * 32 + D0, x); A.x += v0.y * x.x; A.y += v0.y * x.y; A.z += v0.y * x.z; A.w += v0.y * x.w; \
        ld4(SRC + c0.z * 32 + D0, x); A.x += v0.z * x.x; A.y += v0.z * x.y; A.z += v0.z * x.z; A.w += v0.z * x.w; \
        ld4(SRC + c0.w * 32 + D0, x); A.x += v0.w * x.x; A.y += v0.w * x.y; A.z += v0.w * x.z; A.w += v0.w * x.w; \
        ld4(SRC + c1.x * 32 + D0, x); A.x += v1.x * x.x; A.y += v1.x * x.y; A.z += v1.x * x.z; A.w += v1.x * x.w; \
        ld4(SRC + c1.y * 32 + D0, x); A.x += v1.y * x.x; A.y += v1.y * x.y; A.z += v1.y * x.z; A.w += v1.y * x.w; \
        ld4(SRC + c1.z * 32 + D0, x); A.x += v1.z * x.x; A.y += v1.z * x.y; A.z += v1.z * x.z; A.w += v1.z * x.w; \
        ld4(SRC + c1.w * 32 + D0, x); A.x += v1.w * x.x; A.y += v1.w * x.y; A.z += v1.w * x.z; A.w += v1.w * x.w; \
    }

// ------------------------------------------------------------ dtype detector
__global__ void k_detect(const void* L, int* flagp) {
    __shared__ int c;
    if (threadIdx.x == 0) c = 0;
    __syncthreads();
    const unsigned short* p = (const unsigned short*)L;
    int bad = 0;
    for (int i = threadIdx.x; i < 8192; i += 256) {
        unsigned int u = p[i];
        float v = __uint_as_float(u << 16);
        if (isnan(v) || isinf(v) || (v != 0.f && (fabsf(v) < 1e-8f || fabsf(v) > 1e4f))) bad = 1;
    }
    atomicOr(&c, bad);
    __syncthreads();
    if (threadIdx.x == 0) *flagp = (c != 0) ? 1 : 0;
}

// ---------------------------------------------------------------- ELL build (rows padded to x8 with zeros)
__global__ __launch_bounds__(256) void k_build_ell(const void* L, const int* flagp,
                                                   float* __restrict__ ell_val,
                                                   int* __restrict__ ell_col,
                                                   int* __restrict__ ell_cnt) {
    int flag = *flagp;
    int row = blockIdx.x;
    __shared__ int cnt;
    if (threadIdx.x == 0) cnt = 0;
    __syncthreads();
    for (int c = threadIdx.x; c < N_; c += 256) {
        float v = ld(L, row * N_ + c, flag);
        if (v != 0.0f) {
            int s = atomicAdd(&cnt, 1);
            if (s < ELLW) { ell_col[row * ELLW + s] = c; ell_val[row * ELLW + s] = v; }
        }
    }
    __syncthreads();
    int c = cnt < ELLW ? cnt : ELLW;
    int c8 = (c + 7) & ~7;
    for (int s = c + threadIdx.x; s < c8; s += 256) { ell_col[row * ELLW + s] = 0; ell_val[row * ELLW + s] = 0.f; }
    if (threadIdx.x == 0) ell_cnt[row] = c8;
}

// ---------------------------------------------------------------- fp32 copies of h-half weights (layout = LDS layout)
__global__ __launch_bounds__(256) void k_prepw(const void* W_gate, const void* W_cand, const int* flagp,
                                               float* __restrict__ wgh, float* __restrict__ wch) {
    int flag = *flagp;
    int tid = blockIdx.x * 256 + threadIdx.x;
    if (tid < 8192) {
        int kk = tid >> 6, c = tid & 63;
        wgh[tid] = ld(W_gate, ((kk >> 5) * 64 + 32 + (kk & 31)) * 64 + c, flag);
    }
    if (tid < 4096) {
        int kk = tid >> 5, c = tid & 31;
        wch[tid] = ld(W_cand, ((kk >> 5) * 64 + 32 + (kk & 31)) * 32 + c, flag);
    }
}

// ---------------------------------------------------------------- se = relu(SE@W1+b1)@W2+b2
__global__ __launch_bounds__(256) void k_se(const void* SE, const void* W1, const void* B1,
                                            const void* W2, const void* B2, const int* flagp,
                                            float* __restrict__ se) {
    __shared__ float w1[1024], w2[1024], c1[32], c2[32];
    __shared__ float srow[8][33], hid[8][33];
    int flag = *flagp;
    int tid = threadIdx.x;
    for (int i = tid; i < 1024; i += 256) { w1[i] = ld(W1, i, flag); w2[i] = ld(W2, i, flag); }
    if (tid < 32) { c1[tid] = ld(B1, tid, flag); c2[tid] = ld(B2, tid, flag); }
    int r = tid >> 5, d = tid & 31;
    int row = blockIdx.x * 8 + r;
    srow[r][d] = ld(SE, row * 32 + d, flag);
    __syncthreads();
    float a = c1[d];
    #pragma unroll
    for (int i = 0; i < 32; ++i) a += srow[r][i] * w1[i * 32 + d];
    hid[r][d] = fmaxf(a, 0.f);
    __syncthreads();
    float o = c2[d];
    #pragma unroll
    for (int i = 0; i < 32; ++i) o += hid[r][i] * w2[i * 32 + d];
    se[row * 32 + d] = o;
}

// ---------------------------------------------------------------- te
__global__ __launch_bounds__(256) void k_te(const int* __restrict__ TE, const void* W1, const void* B1,
                                            const void* W2, const void* B2, const int* flagp,
                                            float* __restrict__ te) {
    __shared__ float w2[1024], c1[32], c2[32];
    __shared__ float hid[8][33];
    int flag = *flagp;
    int tid = threadIdx.x;
    for (int i = tid; i < 1024; i += 256) w2[i] = ld(W2, i, flag);
    if (tid < 32) { c1[tid] = ld(B1, tid, flag); c2[tid] = ld(B2, tid, flag); }
    __syncthreads();
    int r = tid >> 5, d = tid & 31;
    int row = blockIdx.x * 8 + r;   // row = b*P + t
    int b = row / P_, t = row % P_;
    int day = TE[(b * (P_ + Q_) + t) * 2 + 0];
    int tod = TE[(b * (P_ + Q_) + t) * 2 + 1];
    float a = ld(W1, day * 32 + d, flag) + ld(W1, (7 + tod) * 32 + d, flag) + c1[d];
    hid[r][d] = fmaxf(a, 0.f);
    __syncthreads();
    float o = c2[d];
    #pragma unroll
    for (int i = 0; i < 32; ++i) o += hid[r][i] * w2[i * 32 + d];
    te[row * 32 + d] = o;
}

// ---------------------------------------------------------------- xt for all (t,b): T0 (fp32) + fold order-0 into GX/CX (fp32, init w/ bias)
__global__ __launch_bounds__(256) void k_xt_fold(const void* X, const void* W_in1, const void* b_in1,
        const void* W_in2, const void* b_in2, const void* W_gate, const void* b_gate,
        const void* W_cand, const void* b_cand,
        const float* __restrict__ se, const float* __restrict__ te, const int* flagp,
        float* __restrict__ T0, float* __restrict__ GX, float* __restrict__ CX) {
    __shared__ float w2[1024], wg0[2048], wc0[1024];
    __shared__ float w1s[32], c1s[32], c2s[32];
    __shared__ float hid[32][33];
    __shared__ float st[32][36];   // [feat][row]
    int flag = *flagp;
    int tid = threadIdx.x;
    for (int i = tid; i < 1024; i += 256) w2[i] = ld(W_in2, i, flag);
    for (int i = tid; i < 2048; i += 256) { int j = i >> 6, c = i & 63; wg0[i] = ld(W_gate, j * 64 + c, flag); }
    for (int i = tid; i < 1024; i += 256) { int j = i >> 5, c = i & 31; wc0[i] = ld(W_cand, j * 32 + c, flag); }
    if (tid < 32) { w1s[tid] = ld(W_in1, tid, flag); c1s[tid] = ld(b_in1, tid, flag); c2s[tid] = ld(b_in2, tid, flag); }
    __syncthreads();
    int sr = tid >> 5, d = tid & 31;
    int g0 = blockIdx.x * 32;
    #pragma unroll
    for (int rr = 0; rr < 4; ++rr) {
        int lrow = sr * 4 + rr;
        int g = g0 + lrow;
        int t = g / (B_ * N_); int rem = g - t * B_ * N_; int b = rem >> 11; int n = rem & (N_ - 1);
        float xv = ld(X, (b * P_ + t) * N_ + n, flag);
        hid[lrow][d] = fmaxf(xv * w1s[d] + c1s[d], 0.f);
    }
    __syncthreads();
    #pragma unroll
    for (int rr = 0; rr < 4; ++rr) {
        int lrow = sr * 4 + rr;
        int g = g0 + lrow;
        int t = g / (B_ * N_); int rem = g - t * B_ * N_; int b = rem >> 11; int n = rem & (N_ - 1);
        float o = c2s[d] + se[n * 32 + d] + te[(b * P_ + t) * 32 + d];
        #pragma unroll
        for (int i = 0; i < 32; ++i) o += hid[lrow][i] * w2[i * 32 + d];
        T0[(size_t)g * 32 + d] = o;
        st[d][lrow] = o;
    }
    __syncthreads();
    int d0 = tid & 31, rg = tid >> 5;   // rows rg*4..+3
    float a0[4], a1[4], ac[4];
    float bg0 = ld(b_gate, d0, flag), bg1 = ld(b_gate, 32 + d0, flag), bcv = ld(b_cand, d0, flag);
    #pragma unroll
    for (int i = 0; i < 4; ++i) { a0[i] = bg0; a1[i] = bg1; ac[i] = bcv; }
    #pragma unroll 4
    for (int j = 0; j < 32; ++j) {
        float4 v = *(const float4*)&st[j][rg * 4];
        float u0 = wg0[j * 64 + d0], u1 = wg0[j * 64 + 32 + d0], uc = wc0[j * 32 + d0];
        a0[0] += v.x * u0; a0[1] += v.y * u0; a0[2] += v.z * u0; a0[3] += v.w * u0;
        a1[0] += v.x * u1; a1[1] += v.y * u1; a1[2] += v.z * u1; a1[3] += v.w * u1;
        ac[0] += v.x * uc; ac[1] += v.y * uc; ac[2] += v.z * uc; ac[3] += v.w * uc;
    }
    #pragma unroll
    for (int i = 0; i < 4; ++i) {
        int g = g0 + rg * 4 + i;
        GX[(size_t)g * 64 + d0] = a0[i];
        GX[(size_t)g * 64 + 32 + d0] = a1[i];
        CX[(size_t)g * 32 + d0] = ac[i];
    }
}

// ---------------------------------------------------------------- Chebyshev hop over 48 slices (fp32, float4 gathers)
// + fused fold order-k (fp32 RMW GX/CX). XCD swizzle: slice = blockIdx % 48
__global__ __launch_bounds__(256) void k_hop_fold(int k, const float* __restrict__ in, const float* __restrict__ prevb,
        float* __restrict__ outT, const void* W_gate, const void* W_cand,
        const float* __restrict__ ell_val, const int* __restrict__ ell_col, const int* __restrict__ ell_cnt,
        const int* flagp, float* __restrict__ GX, float* __restrict__ CX) {
    __shared__ float wgk[2048], wck[1024];
    __shared__ float st[32][36];
    int flag = *flagp;
    int tid = threadIdx.x;
    for (int i = tid; i < 2048; i += 256) { int j = i >> 6, c = i & 63; wgk[i] = ld(W_gate, (k * 64 + j) * 64 + c, flag); }
    for (int i = tid; i < 1024; i += 256) { int j = i >> 5, c = i & 31; wck[i] = ld(W_cand, (k * 64 + j) * 32 + c, flag); }
    int dq = tid & 7, rl = tid >> 3;     // one row, 4 d's per thread
    int d0 = dq * 4;
    int slice = blockIdx.x % 48;
    int rb = blockIdx.x / 48;
    const float* inS = in + (size_t)slice * (N_ * 32);
    __syncthreads();
    {
        int row = rb * 32 + rl;
        int cnt = ell_cnt[row];
        const int* cols = ell_col + row * ELLW;
        const float* vals = ell_val + row * ELLW;
        float4 a = {0.f, 0.f, 0.f, 0.f};
        for (int i = 0; i < cnt; i += 8) GATHER8(inS, d0, a)
        size_t idx = (size_t)slice * (N_ * 32) + (size_t)row * 32 + d0;
        float4 t = a;
        if (prevb) {
            float4 p; ld4(prevb + idx, p);
            t.x = 2.f * a.x - p.x; t.y = 2.f * a.y - p.y;
            t.z = 2.f * a.z - p.z; t.w = 2.f * a.w - p.w;
        }
        if (outT) *(float4*)(outT + idx) = t;
        st[d0][rl] = t.x; st[d0 + 1][rl] = t.y; st[d0 + 2][rl] = t.z; st[d0 + 3][rl] = t.w;
    }
    __syncthreads();
    int d = tid & 31, rg = tid >> 5;
    int grow0 = slice * N_ + rb * 32 + rg * 4;
    float a0[4], a1[4], ac[4];
    #pragma unroll
    for (int i = 0; i < 4; ++i) {
        int g = grow0 + i;
        a0[i] = GX[(size_t)g * 64 + d];
        a1[i] = GX[(size_t)g * 64 + 32 + d];
        ac[i] = CX[(size_t)g * 32 + d];
    }
    #pragma unroll 4
    for (int j = 0; j < 32; ++j) {
        float4 v = *(const float4*)&st[j][rg * 4];
        float u0 = wgk[j * 64 + d], u1 = wgk[j * 64 + 32 + d], uc = wck[j * 32 + d];
        a0[0] += v.x * u0; a0[1] += v.y * u0; a0[2] += v.z * u0; a0[3] += v.w * u0;
        a1[0] += v.x * u1; a1[1] += v.y * u1; a1[2] += v.z * u1; a1[3] += v.w * u1;
        ac[0] += v.x * uc; ac[1] += v.y * uc; ac[2] += v.z * uc; ac[3] += v.w * uc;
    }
    #pragma unroll
    for (int i = 0; i < 4; ++i) {
        int g = grow0 + i;
        GX[(size_t)g * 64 + d] = a0[i];
        GX[(size_t)g * 64 + 32 + d] = a1[i];
        CX[(size_t)g * 32 + d] = ac[i];
    }
}

// ---------------------------------------------------------------- scan hop: 256 blocks x 32 rows; float4 gathers
__global__ __launch_bounds__(256) void k_spmm1(const float* __restrict__ in, const float* __restrict__ prevb,
                                               float* __restrict__ out,
                                               const float* __restrict__ ell_val, const int* __restrict__ ell_col,
                                               const int* __restrict__ ell_cnt) {
    int dq = threadIdx.x & 7, rl = threadIdx.x >> 3;
    int d0 = dq * 4;
    int slice = blockIdx.x & 3;
    int rb = blockIdx.x >> 2;
    int row = rb * 32 + rl;
    const float* inS = in + (size_t)slice * (N_ * 32);
    int cnt = ell_cnt[row];
    const int* cols = ell_col + row * ELLW;
    const float* vals = ell_val + row * ELLW;
    float4 a = {0.f, 0.f, 0.f, 0.f};
    for (int i = 0; i < cnt; i += 8) GATHER8(inS, d0, a)
    size_t idx = (size_t)slice * (N_ * 32) + (size_t)row * 32 + d0;
    float4 t = a;
    if (prevb) {
        float4 p; ld4(prevb + idx, p);
        t.x = 2.f * a.x - p.x; t.y = 2.f * a.y - p.y;
        t.z = 2.f * a.z - p.z; t.w = 2.f * a.w - p.w;
    }
    *(float4*)(out + idx) = t;
}

// ---------------------------------------------------------------- step 0: H = (1 - sigmoid(GX0_u)) * tanh(CX0)   (h0 == 0 exactly)
__global__ __launch_bounds__(256) void k_step0(const float* __restrict__ GX, const float* __restrict__ CX,
                                               float* __restrict__ H) {
    int gid = blockIdx.x * 256 + threadIdx.x;
    int d = gid & 31, g = gid >> 5;
    float uv = 1.f / (1.f + expf(-GX[(size_t)g * 64 + 32 + d]));
    float c = tanhf(CX[(size_t)g * 32 + d]);
    H[(size_t)g * 32 + d] = (1.f - uv) * c;
}

// ---------------------------------------------------------------- gate: 256 blocks x 32 rows; float4 gathers + GEMM + sigmoid
__global__ __launch_bounds__(256) void k_gate(const float* __restrict__ H, const float* __restrict__ HC1,
                                              const float* __restrict__ HC2, const float* __restrict__ GXt,
                                              const float* __restrict__ wgh,
                                              const float* __restrict__ ell_val, const int* __restrict__ ell_col,
                                              const int* __restrict__ ell_cnt,
                                              bf16* __restrict__ U, float* __restrict__ RH) {
    __shared__ float wg[8192];
    __shared__ float st[128][36];
    int tid = threadIdx.x;
    {
        const float4* src = (const float4*)wgh;
        float4* dst = (float4*)wg;
        #pragma unroll
        for (int i = 0; i < 8; ++i) dst[tid + i * 256] = src[tid + i * 256];
    }
    int dq = tid & 7, rl = tid >> 3, d0 = dq * 4;
    int b = blockIdx.x & 3;
    int rb = blockIdx.x >> 2;
    const float* H2s = HC2 + (size_t)b * (N_ * 32);
    {
        int n = rb * 32 + rl;
        size_t idx = ((size_t)b * N_ + n) * 32 + d0;
        float4 hv, h1, h2;
        ld4(H + idx, hv);
        ld4(HC1 + idx, h1);
        ld4(HC2 + idx, h2);
        int cnt = ell_cnt[n];
        const int* cols = ell_col + n * ELLW;
        const float* vals = ell_val + n * ELLW;
        float4 a = {0.f, 0.f, 0.f, 0.f};
        for (int j = 0; j < cnt; j += 8) { int i = j; GATHER8(H2s, d0, a) }
        st[d0][rl] = hv.x; st[d0 + 1][rl] = hv.y; st[d0 + 2][rl] = hv.z; st[d0 + 3][rl] = hv.w;
        st[32 + d0][rl] = h1.x; st[32 + d0 + 1][rl] = h1.y; st[32 + d0 + 2][rl] = h1.z; st[32 + d0 + 3][rl] = h1.w;
        st[64 + d0][rl] = h2.x; st[64 + d0 + 1][rl] = h2.y; st[64 + d0 + 2][rl] = h2.z; st[64 + d0 + 3][rl] = h2.w;
        st[96 + d0][rl] = 2.f * a.x - h1.x; st[96 + d0 + 1][rl] = 2.f * a.y - h1.y;
        st[96 + d0 + 2][rl] = 2.f * a.z - h1.z; st[96 + d0 + 3][rl] = 2.f * a.w - h1.w;
    }
    __syncthreads();
    int d = tid & 31, rg = tid >> 5;
    int g0 = b * N_ + rb * 32 + rg * 4;
    float a0[4], a1[4];
    #pragma unroll
    for (int i = 0; i < 4; ++i) {
        a0[i] = GXt[(size_t)(g0 + i) * 64 + d];
        a1[i] = GXt[(size_t)(g0 + i) * 64 + 32 + d];
    }
    #pragma unroll 4
    for (int kk = 0; kk < 128; ++kk) {
        float4 v = *(const float4*)&st[kk][rg * 4];
        float u0 = wg[kk * 64 + d], u1 = wg[kk * 64 + 32 + d];
        a0[0] += v.x * u0; a0[1] += v.y * u0; a0[2] += v.z * u0; a0[3] += v.w * u0;
        a1[0] += v.x * u1; a1[1] += v.y * u1; a1[2] += v.z * u1; a1[3] += v.w * u1;
    }
    #pragma unroll
    for (int i = 0; i < 4; ++i) {
        float rv = 1.f / (1.f + expf(-a0[i]));
        float uv = 1.f / (1.f + expf(-a1[i]));
        float hv = st[d][rg * 4 + i];
        size_t idx = (size_t)(g0 + i) * 32 + d;
        U[idx] = __float2bfloat16(uv);
        RH[idx] = rv * hv;
    }
}

// ---------------------------------------------------------------- cand: 256 blocks x 32 rows; float4 gathers + GEMM + tanh + update
__global__ __launch_bounds__(256) void k_cand(const float* __restrict__ RHv, const float* __restrict__ RC1,
                                              const float* __restrict__ RC2, const float* __restrict__ CXt,
                                              const float* __restrict__ wch,
                                              const float* __restrict__ ell_val, const int* __restrict__ ell_col,
                                              const int* __restrict__ ell_cnt,
                                              const bf16* __restrict__ U, float* __restrict__ H) {
    __shared__ float wc[4096];
    __shared__ float st[128][36];
    int tid = threadIdx.x;
    {
        const float4* src = (const float4*)wch;
        float4* dst = (float4*)wc;
        #pragma unroll
        for (int i = 0; i < 4; ++i) dst[tid + i * 256] = src[tid + i * 256];
    }
    int dq = tid & 7, rl = tid >> 3, d0 = dq * 4;
    int b = blockIdx.x & 3;
    int rb = blockIdx.x >> 2;
    const float* R2s = RC2 + (size_t)b * (N_ * 32);
    {
        int n = rb * 32 + rl;
        size_t idx = ((size_t)b * N_ + n) * 32 + d0;
        float4 rh, r1, r2;
        ld4(RHv + idx, rh);
        ld4(RC1 + idx, r1);
        ld4(RC2 + idx, r2);
        int cnt = ell_cnt[n];
        const int* cols = ell_col + n * ELLW;
        const float* vals = ell_val + n * ELLW;
        float4 a = {0.f, 0.f, 0.f, 0.f};
        for (int j = 0; j < cnt; j += 8) { int i = j; GATHER8(R2s, d0, a) }
        st[d0][rl] = rh.x; st[d0 + 1][rl] = rh.y; st[d0 + 2][rl] = rh.z; st[d0 + 3][rl] = rh.w;
        st[32 + d0][rl] = r1.x; st[32 + d0 + 1][rl] = r1.y; st[32 + d0 + 2][rl] = r1.z; st[32 + d0 + 3][rl] = r1.w;
        st[64 + d0][rl] = r2.x; st[64 + d0 + 1][rl] = r2.y; st[64 + d0 + 2][rl] = r2.z; st[64 + d0 + 3][rl] = r2.w;
        st[96 + d0][rl] = 2.f * a.x - r1.x; st[96 + d0 + 1][rl] = 2.f * a.y - r1.y;
        st[96 + d0 + 2][rl] = 2.f * a.z - r1.z; st[96 + d0 + 3][rl] = 2.f * a.w - r1.w;
    }
    __syncthreads();
    int d = tid & 31, rg = tid >> 5;
    int g0 = b * N_ + rb * 32 + rg * 4;
    float ac[4];
    #pragma unroll
    for (int i = 0; i < 4; ++i) ac[i] = CXt[(size_t)(g0 + i) * 32 + d];
    #pragma unroll 4
    for (int kk = 0; kk < 128; ++kk) {
        float4 v = *(const float4*)&st[kk][rg * 4];
        float uc = wc[kk * 32 + d];
        ac[0] += v.x * uc; ac[1] += v.y * uc; ac[2] += v.z * uc; ac[3] += v.w * uc;
    }
    #pragma unroll
    for (int i = 0; i < 4; ++i) {
        float c = tanhf(ac[i]);
        size_t idx = (size_t)(g0 + i) * 32 + d;
        float uv = tf(U[idx]);
        float hv = H[idx];
        H[idx] = uv * hv + (1.f - uv) * c;
    }
}

// ---------------------------------------------------------------- output head
__global__ __launch_bounds__(256) void k_out(const float* __restrict__ H, const void* W1, const void* B1,
                                             const void* W2, const void* B2, const int* flagp,
                                             void* __restrict__ out) {
    __shared__ float w1[1024], w2[384], c1[32], c2[12];
    int flag = *flagp;
    int tid = threadIdx.x;
    for (int i = tid; i < 1024; i += 256) w1[i] = ld(W1, i, flag);
    for (int i = tid; i < 384; i += 256) w2[i] = ld(W2, i, flag);
    if (tid < 32) c1[tid] = ld(B1, tid, flag);
    if (tid < 12) c2[tid] = ld(B2, tid, flag);
    __syncthreads();
    int gid = blockIdx.x * 256 + tid;
    int b = gid / N_, n = gid % N_;
    float hrow[32];
    #pragma unroll
    for (int i = 0; i < 32; ++i) hrow[i] = H[(size_t)(b * N_ + n) * 32 + i];
    float hid[32];
    #pragma unroll
    for (int j = 0; j < 32; ++j) {
        float a = c1[j];
        #pragma unroll
        for (int i = 0; i < 32; ++i) a += hrow[i] * w1[i * 32 + j];
        hid[j] = fmaxf(a, 0.f);
    }
    for (int q = 0; q < 12; ++q) {
        float a = c2[q];
        #pragma unroll
        for (int j = 0; j < 32; ++j) a += hid[j] * w2[j * 12 + q];
        size_t idx = ((size_t)b * Q_ + q) * N_ + n;
        if (flag) ((float*)out)[idx] = a;
        else ((bf16*)out)[idx] = __float2bfloat16(a);
    }
}

extern "C" void kernel_launch(void* const* d_in, const int* in_sizes, int n_in,
                              void* d_out, int out_size, void* d_ws, size_t ws_size,
                              hipStream_t stream) {
    const void* X      = d_in[0];
    const int*  TE     = (const int*)d_in[1];
    const void* L      = d_in[2];
    const void* SEi    = d_in[3];
    const void* W_se1  = d_in[4];
    const void* b_se1  = d_in[5];
    const void* W_se2  = d_in[6];
    const void* b_se2  = d_in[7];
    const void* W_te1  = d_in[8];
    const void* b_te1  = d_in[9];
    const void* W_te2  = d_in[10];
    const void* b_te2  = d_in[11];
    const void* W_in1  = d_in[12];
    const void* b_in1  = d_in[13];
    const void* W_in2  = d_in[14];
    const void* b_in2  = d_in[15];
    const void* W_gate = d_in[16];
    const void* b_gate = d_in[17];
    const void* W_cand = d_in[18];
    const void* b_cand = d_in[19];
    const void* W_out1 = d_in[20];
    const void* b_out1 = d_in[21];
    const void* W_out2 = d_in[22];
    const void* b_out2 = d_in[23];

    // ---- workspace layout (fp32 units) ----
    float* ws = (float*)d_ws;
    size_t o = 0;
    int*   flagp   = (int*)(ws + o); o += 16;
    float* ell_val = ws + o; o += (size_t)N_ * ELLW;
    int*   ell_col = (int*)(ws + o); o += (size_t)N_ * ELLW;
    int*   ell_cnt = (int*)(ws + o); o += N_;
    float* se = ws + o; o += (size_t)N_ * 32;
    float* te = ws + o; o += (size_t)B_ * P_ * 32;
    float* wgh = ws + o; o += 8192;
    float* wch = ws + o; o += 4096;
    const size_t TSZ = (size_t)P_ * B_ * N_ * 32;       // elems
    float* Ta = ws + o; o += TSZ;                       // T0, later T2 (in place)
    float* Tb = ws + o; o += TSZ;                       // T1
    float* GX = ws + o; o += (size_t)P_ * B_ * N_ * 64; // fp32 (4x RMW accumulation)
    float* CX = ws + o; o += TSZ;                       // fp32
    const size_t HSZ = (size_t)B_ * N_ * 32;            // elems
    float* H   = ws + o; o += HSZ;                      // fp32 recurrent state
    float* HC1 = ws + o; o += HSZ;
    float* HC2 = ws + o; o += HSZ;
    float* RH  = ws + o; o += HSZ;
    float* RC1 = ws + o; o += HSZ;
    float* RC2 = ws + o; o += HSZ;
    bf16* Ub  = (bf16*)(ws + o); o += HSZ / 2;

    k_detect<<<1, 256, 0, stream>>>(L, flagp);
    k_build_ell<<<N_, 256, 0, stream>>>(L, flagp, ell_val, ell_col, ell_cnt);
    k_prepw<<<32, 256, 0, stream>>>(W_gate, W_cand, flagp, wgh, wch);
    k_se<<<N_ / 8, 256, 0, stream>>>(SEi, W_se1, b_se1, W_se2, b_se2, flagp, se);
    k_te<<<(B_ * P_) / 8, 256, 0, stream>>>(TE, W_te1, b_te1, W_te2, b_te2, flagp, te);

    // x-side Chebyshev + fold (once, batched over all t,b)
    const int GBIG = P_ * B_ * N_ / 32;     // 3072
    k_xt_fold<<<GBIG, 256, 0, stream>>>(X, W_in1, b_in1, W_in2, b_in2, W_gate, b_gate, W_cand, b_cand,
                                        se, te, flagp, Ta, GX, CX);
    k_hop_fold<<<GBIG, 256, 0, stream>>>(1, Ta, nullptr, Tb, W_gate, W_cand,
                                         ell_val, ell_col, ell_cnt, flagp, GX, CX);
    k_hop_fold<<<GBIG, 256, 0, stream>>>(2, Tb, Ta, Ta, W_gate, W_cand,
                                         ell_val, ell_col, ell_cnt, flagp, GX, CX);
    k_hop_fold<<<GBIG, 256, 0, stream>>>(3, Ta, Tb, nullptr, W_gate, W_cand,
                                         ell_val, ell_col, ell_cnt, flagp, GX, CX);

    // t = 0: H starts at exactly zero -> single elementwise step
    k_step0<<<(B_ * N_ * 32) / 256, 256, 0, stream>>>(GX, CX, H);

    for (int t = 1; t < P_; ++t) {
        const float* GXt = GX + (size_t)t * B_ * N_ * 64;
        const float* CXt = CX + (size_t)t * B_ * N_ * 32;
        k_spmm1<<<B_ * N_ / 32, 256, 0, stream>>>(H, nullptr, HC1, ell_val, ell_col, ell_cnt);
        k_spmm1<<<B_ * N_ / 32, 256, 0, stream>>>(HC1, H, HC2, ell_val, ell_col, ell_cnt);
        k_gate<<<B_ * N_ / 32, 256, 0, stream>>>(H, HC1, HC2, GXt, wgh,
                                                 ell_val, ell_col, ell_cnt, Ub, RH);
        k_spmm1<<<B_ * N_ / 32, 256, 0, stream>>>(RH, nullptr, RC1, ell_val, ell_col, ell_cnt);
        k_spmm1<<<B_ * N_ / 32, 256, 0, stream>>>(RC1, RH, RC2, ell_val, ell_col, ell_cnt);
        k_cand<<<B_ * N_ / 32, 256, 0, stream>>>(RH, RC1, RC2, CXt, wch,
                                                 ell_val, ell_col, ell_cnt, Ub, H);
    }
    k_out<<<B_ * N_ / 256, 256, 0, stream>>>(H, W_out1, b_out1, W_out2, b_out2, flagp, (void*)d_out);
}

// Round 11
// 733.762 us; speedup vs baseline: 1.0542x; 1.0542x over previous
//
#include <hip/hip_runtime.h>
#include <hip/hip_bf16.h>

#define B_ 4
#define P_ 12
#define Q_ 12
#define N_ 2048
#define D_ 32
#define ELLW 96

typedef __hip_bfloat16 bf16;

// Dual-path input load: flag==0 -> bf16 storage, flag==1 -> fp32 storage.
__device__ __forceinline__ float ld(const void* p, int i, int flag) {
    if (flag) return ((const float*)p)[i];
    unsigned int u = ((const unsigned short*)p)[i];
    return __uint_as_float(u << 16);
}

__device__ __forceinline__ float tf(float x) { return x; }
__device__ __forceinline__ float tf(bf16 x) { return __bfloat162float(x); }
__device__ __forceinline__ float bflo(unsigned int u) { return __uint_as_float(u << 16); }
__device__ __forceinline__ float bfhi(unsigned int u) { return __uint_as_float(u & 0xffff0000u); }
__device__ __forceinline__ unsigned int pk2(float a, float b) {
    bf16 x = __float2bfloat16(a), y = __float2bfloat16(b);
    unsigned short lo = *(unsigned short*)&x, hi = *(unsigned short*)&y;
    return (unsigned int)lo | ((unsigned int)hi << 16);
}
// packed pair load: bf16 source -> dword, float source -> float2
__device__ __forceinline__ void ld2(const bf16* p, float& a, float& b) {
    unsigned int u = *(const unsigned int*)p; a = bflo(u); b = bfhi(u);
}
__device__ __forceinline__ void ld2(const float* p, float& a, float& b) {
    float2 v = *(const float2*)p; a = v.x; b = v.y;
}
// 4-element bf16 load/store (dwordx2)
__device__ __forceinline__ void ld4b(const bf16* p, float4& v) {
    uint2 u = *(const uint2*)p;
    v.x = bflo(u.x); v.y = bfhi(u.x); v.z = bflo(u.y); v.w = bfhi(u.y);
}
__device__ __forceinline__ void st4b(bf16* p, float4 v) {
    uint2 o; o.x = pk2(v.x, v.y); o.y = pk2(v.z, v.w);
    *(uint2*)p = o;
}

// ------------------------------------------------------------ dtype detector
__global__ void k_detect(const void* L, int* flagp) {
    __shared__ int c;
    if (threadIdx.x == 0) c = 0;
    __syncthreads();
    const unsigned short* p = (const unsigned short*)L;
    int bad = 0;
    for (int i = threadIdx.x; i < 8192; i += 256) {
        unsigned int u = p[i];
        float v = __uint_as_float(u << 16);
        if (isnan(v) || isinf(v) || (v != 0.f && (fabsf(v) < 1e-8f || fabsf(v) > 1e4f))) bad = 1;
    }
    atomicOr(&c, bad);
    __syncthreads();
    if (threadIdx.x == 0) *flagp = (c != 0) ? 1 : 0;
}

// ---------------------------------------------------------------- ELL build (rows padded to x8 with zeros)
__global__ __launch_bounds__(256) void k_build_ell(const void* L, const int* flagp,
                                                   float* __restrict__ ell_val,
                                                   int* __restrict__ ell_col,
                                                   int* __restrict__ ell_cnt) {
    int flag = *flagp;
    int row = blockIdx.x;
    __shared__ int cnt;
    if (threadIdx.x == 0) cnt = 0;
    __syncthreads();
    for (int c = threadIdx.x; c < N_; c += 256) {
        float v = ld(L, row * N_ + c, flag);
        if (v != 0.0f) {
            int s = atomicAdd(&cnt, 1);
            if (s < ELLW) { ell_col[row * ELLW + s] = c; ell_val[row * ELLW + s] = v; }
        }
    }
    __syncthreads();
    int c = cnt < ELLW ? cnt : ELLW;
    int c8 = (c + 7) & ~7;
    for (int s = c + threadIdx.x; s < c8; s += 256) { ell_col[row * ELLW + s] = 0; ell_val[row * ELLW + s] = 0.f; }
    if (threadIdx.x == 0) ell_cnt[row] = c8;
}

// ---------------------------------------------------------------- fp32 copies of h-half weights (layout = LDS layout)
__global__ __launch_bounds__(256) void k_prepw(const void* W_gate, const void* W_cand, const int* flagp,
                                               float* __restrict__ wgh, float* __restrict__ wch) {
    int flag = *flagp;
    int tid = blockIdx.x * 256 + threadIdx.x;
    if (tid < 8192) {
        int kk = tid >> 6, c = tid & 63;
        wgh[tid] = ld(W_gate, ((kk >> 5) * 64 + 32 + (kk & 31)) * 64 + c, flag);
    }
    if (tid < 4096) {
        int kk = tid >> 5, c = tid & 31;
        wch[tid] = ld(W_cand, ((kk >> 5) * 64 + 32 + (kk & 31)) * 32 + c, flag);
    }
}

// ---------------------------------------------------------------- se = relu(SE@W1+b1)@W2+b2
__global__ __launch_bounds__(256) void k_se(const void* SE, const void* W1, const void* B1,
                                            const void* W2, const void* B2, const int* flagp,
                                            float* __restrict__ se) {
    __shared__ float w1[1024], w2[1024], c1[32], c2[32];
    __shared__ float srow[8][33], hid[8][33];
    int flag = *flagp;
    int tid = threadIdx.x;
    for (int i = tid; i < 1024; i += 256) { w1[i] = ld(W1, i, flag); w2[i] = ld(W2, i, flag); }
    if (tid < 32) { c1[tid] = ld(B1, tid, flag); c2[tid] = ld(B2, tid, flag); }
    int r = tid >> 5, d = tid & 31;
    int row = blockIdx.x * 8 + r;
    srow[r][d] = ld(SE, row * 32 + d, flag);
    __syncthreads();
    float a = c1[d];
    #pragma unroll
    for (int i = 0; i < 32; ++i) a += srow[r][i] * w1[i * 32 + d];
    hid[r][d] = fmaxf(a, 0.f);
    __syncthreads();
    float o = c2[d];
    #pragma unroll
    for (int i = 0; i < 32; ++i) o += hid[r][i] * w2[i * 32 + d];
    se[row * 32 + d] = o;
}

// ---------------------------------------------------------------- te
__global__ __launch_bounds__(256) void k_te(const int* __restrict__ TE, const void* W1, const void* B1,
                                            const void* W2, const void* B2, const int* flagp,
                                            float* __restrict__ te) {
    __shared__ float w2[1024], c1[32], c2[32];
    __shared__ float hid[8][33];
    int flag = *flagp;
    int tid = threadIdx.x;
    for (int i = tid; i < 1024; i += 256) w2[i] = ld(W2, i, flag);
    if (tid < 32) { c1[tid] = ld(B1, tid, flag); c2[tid] = ld(B2, tid, flag); }
    __syncthreads();
    int r = tid >> 5, d = tid & 31;
    int row = blockIdx.x * 8 + r;   // row = b*P + t
    int b = row / P_, t = row % P_;
    int day = TE[(b * (P_ + Q_) + t) * 2 + 0];
    int tod = TE[(b * (P_ + Q_) + t) * 2 + 1];
    float a = ld(W1, day * 32 + d, flag) + ld(W1, (7 + tod) * 32 + d, flag) + c1[d];
    hid[r][d] = fmaxf(a, 0.f);
    __syncthreads();
    float o = c2[d];
    #pragma unroll
    for (int i = 0; i < 32; ++i) o += hid[r][i] * w2[i * 32 + d];
    te[row * 32 + d] = o;
}

// ---------------------------------------------------------------- xt for all (t,b): T0 (bf16) + fold order-0 into GX/CX (fp32, init w/ bias)
__global__ __launch_bounds__(256) void k_xt_fold(const void* X, const void* W_in1, const void* b_in1,
        const void* W_in2, const void* b_in2, const void* W_gate, const void* b_gate,
        const void* W_cand, const void* b_cand,
        const float* __restrict__ se, const float* __restrict__ te, const int* flagp,
        bf16* __restrict__ T0, float* __restrict__ GX, float* __restrict__ CX) {
    __shared__ float w2[1024], wg0[2048], wc0[1024];
    __shared__ float w1s[32], c1s[32], c2s[32];
    __shared__ float hid[32][33];
    __shared__ float st[32][36];   // [feat][row]
    int flag = *flagp;
    int tid = threadIdx.x;
    for (int i = tid; i < 1024; i += 256) w2[i] = ld(W_in2, i, flag);
    for (int i = tid; i < 2048; i += 256) { int j = i >> 6, c = i & 63; wg0[i] = ld(W_gate, j * 64 + c, flag); }
    for (int i = tid; i < 1024; i += 256) { int j = i >> 5, c = i & 31; wc0[i] = ld(W_cand, j * 32 + c, flag); }
    if (tid < 32) { w1s[tid] = ld(W_in1, tid, flag); c1s[tid] = ld(b_in1, tid, flag); c2s[tid] = ld(b_in2, tid, flag); }
    __syncthreads();
    int sr = tid >> 5, d = tid & 31;
    int g0 = blockIdx.x * 32;
    #pragma unroll
    for (int rr = 0; rr < 4; ++rr) {
        int lrow = sr * 4 + rr;
        int g = g0 + lrow;
        int t = g / (B_ * N_); int rem = g - t * B_ * N_; int b = rem >> 11; int n = rem & (N_ - 1);
        float xv = ld(X, (b * P_ + t) * N_ + n, flag);
        hid[lrow][d] = fmaxf(xv * w1s[d] + c1s[d], 0.f);
    }
    __syncthreads();
    #pragma unroll
    for (int rr = 0; rr < 4; ++rr) {
        int lrow = sr * 4 + rr;
        int g = g0 + lrow;
        int t = g / (B_ * N_); int rem = g - t * B_ * N_; int b = rem >> 11; int n = rem & (N_ - 1);
        float o = c2s[d] + se[n * 32 + d] + te[(b * P_ + t) * 32 + d];
        #pragma unroll
        for (int i = 0; i < 32; ++i) o += hid[lrow][i] * w2[i * 32 + d];
        T0[(size_t)g * 32 + d] = __float2bfloat16(o);
        st[d][lrow] = o;
    }
    __syncthreads();
    int d0 = tid & 31, rg = tid >> 5;   // rows rg*4..+3
    float a0[4], a1[4], ac[4];
    float bg0 = ld(b_gate, d0, flag), bg1 = ld(b_gate, 32 + d0, flag), bcv = ld(b_cand, d0, flag);
    #pragma unroll
    for (int i = 0; i < 4; ++i) { a0[i] = bg0; a1[i] = bg1; ac[i] = bcv; }
    #pragma unroll 4
    for (int j = 0; j < 32; ++j) {
        float4 v = *(const float4*)&st[j][rg * 4];
        float u0 = wg0[j * 64 + d0], u1 = wg0[j * 64 + 32 + d0], uc = wc0[j * 32 + d0];
        a0[0] += v.x * u0; a0[1] += v.y * u0; a0[2] += v.z * u0; a0[3] += v.w * u0;
        a1[0] += v.x * u1; a1[1] += v.y * u1; a1[2] += v.z * u1; a1[3] += v.w * u1;
        ac[0] += v.x * uc; ac[1] += v.y * uc; ac[2] += v.z * uc; ac[3] += v.w * uc;
    }
    #pragma unroll
    for (int i = 0; i < 4; ++i) {
        int g = g0 + rg * 4 + i;
        GX[(size_t)g * 64 + d0] = a0[i];
        GX[(size_t)g * 64 + 32 + d0] = a1[i];
        CX[(size_t)g * 32 + d0] = ac[i];
    }
}

// ---------------------------------------------------------------- Chebyshev hop over 48 slices (bf16, d-quad gathers)
// + fused fold order-k (fp32 RMW GX/CX). XCD swizzle: slice = blockIdx % 48
__global__ __launch_bounds__(256) void k_hop_fold(int k, const bf16* __restrict__ in, const bf16* __restrict__ prevb,
        bf16* __restrict__ outT, const void* W_gate, const void* W_cand,
        const float* __restrict__ ell_val, const int* __restrict__ ell_col, const int* __restrict__ ell_cnt,
        const int* flagp, float* __restrict__ GX, float* __restrict__ CX) {
    __shared__ float wgk[2048], wck[1024];
    __shared__ float st[32][36];
    int flag = *flagp;
    int tid = threadIdx.x;
    for (int i = tid; i < 2048; i += 256) { int j = i >> 6, c = i & 63; wgk[i] = ld(W_gate, (k * 64 + j) * 64 + c, flag); }
    for (int i = tid; i < 1024; i += 256) { int j = i >> 5, c = i & 31; wck[i] = ld(W_cand, (k * 64 + j) * 32 + c, flag); }
    int dq = tid & 7, rl = tid >> 3;     // one row, 4 d's per thread
    int d0 = dq * 4;
    int slice = blockIdx.x % 48;
    int rb = blockIdx.x / 48;
    const bf16* inS = in + (size_t)slice * (N_ * 32);
    __syncthreads();
    {
        int row = rb * 32 + rl;
        int cnt = ell_cnt[row];
        const int* cols = ell_col + row * ELLW;
        const float* vals = ell_val + row * ELLW;
        float4 a = {0.f, 0.f, 0.f, 0.f};
        for (int i = 0; i < cnt; i += 8) {
            int4 c0 = *(const int4*)(cols + i);
            int4 c1 = *(const int4*)(cols + i + 4);
            float4 v0 = *(const float4*)(vals + i);
            float4 v1 = *(const float4*)(vals + i + 4);
            float4 x;
            ld4b(inS + c0.x * 32 + d0, x); a.x += v0.x * x.x; a.y += v0.x * x.y; a.z += v0.x * x.z; a.w += v0.x * x.w;
            ld4b(inS + c0.y * 32 + d0, x); a.x += v0.y * x.x; a.y += v0.y * x.y; a.z += v0.y * x.z; a.w += v0.y * x.w;
            ld4b(inS + c0.z * 32 + d0, x); a.x += v0.z * x.x; a.y += v0.z * x.y; a.z += v0.z * x.z; a.w += v0.z * x.w;
            ld4b(inS + c0.w * 32 + d0, x); a.x += v0.w * x.x; a.y += v0.w * x.y; a.z += v0.w * x.z; a.w += v0.w * x.w;
            ld4b(inS + c1.x * 32 + d0, x); a.x += v1.x * x.x; a.y += v1.x * x.y; a.z += v1.x * x.z; a.w += v1.x * x.w;
            ld4b(inS + c1.y * 32 + d0, x); a.x += v1.y * x.x; a.y += v1.y * x.y; a.z += v1.y * x.z; a.w += v1.y * x.w;
            ld4b(inS + c1.z * 32 + d0, x); a.x += v1.z * x.x; a.y += v1.z * x.y; a.z += v1.z * x.z; a.w += v1.z * x.w;
            ld4b(inS + c1.w * 32 + d0, x); a.x += v1.w * x.x; a.y += v1.w * x.y; a.z += v1.w * x.z; a.w += v1.w * x.w;
        }
        size_t idx = (size_t)slice * (N_ * 32) + (size_t)row * 32 + d0;
        float4 t = a;
        if (prevb) {
            float4 p; ld4b(prevb + idx, p);
            t.x = 2.f * a.x - p.x; t.y = 2.f * a.y - p.y;
            t.z = 2.f * a.z - p.z; t.w = 2.f * a.w - p.w;
        }
        if (outT) st4b(outT + idx, t);
        st[d0][rl] = t.x; st[d0 + 1][rl] = t.y; st[d0 + 2][rl] = t.z; st[d0 + 3][rl] = t.w;
    }
    __syncthreads();
    int d = tid & 31, rg = tid >> 5;
    int grow0 = slice * N_ + rb * 32 + rg * 4;
    float a0[4], a1[4], ac[4];
    #pragma unroll
    for (int i = 0; i < 4; ++i) {
        int g = grow0 + i;
        a0[i] = GX[(size_t)g * 64 + d];
        a1[i] = GX[(size_t)g * 64 + 32 + d];
        ac[i] = CX[(size_t)g * 32 + d];
    }
    #pragma unroll 4
    for (int j = 0; j < 32; ++j) {
        float4 v = *(const float4*)&st[j][rg * 4];
        float u0 = wgk[j * 64 + d], u1 = wgk[j * 64 + 32 + d], uc = wck[j * 32 + d];
        a0[0] += v.x * u0; a0[1] += v.y * u0; a0[2] += v.z * u0; a0[3] += v.w * u0;
        a1[0] += v.x * u1; a1[1] += v.y * u1; a1[2] += v.z * u1; a1[3] += v.w * u1;
        ac[0] += v.x * uc; ac[1] += v.y * uc; ac[2] += v.z * uc; ac[3] += v.w * uc;
    }
    #pragma unroll
    for (int i = 0; i < 4; ++i) {
        int g = grow0 + i;
        GX[(size_t)g * 64 + d] = a0[i];
        GX[(size_t)g * 64 + 32 + d] = a1[i];
        CX[(size_t)g * 32 + d] = ac[i];
    }
}

// ---------------------------------------------------------------- scan hop: 512 blocks = 4 slices x 128 rowblocks; d-pair gathers (8 waves/CU)
template<typename TI, typename TP>
__global__ __launch_bounds__(256) void k_spmm1(const TI* __restrict__ in, const TP* __restrict__ prevb,
                                               bf16* __restrict__ out,
                                               const float* __restrict__ ell_val, const int* __restrict__ ell_col,
                                               const int* __restrict__ ell_cnt) {
    int dp = threadIdx.x & 15, rs = threadIdx.x >> 4;   // 16 rows/block
    int slice = blockIdx.x & 3;
    int rb = blockIdx.x >> 2;
    int row = rb * 16 + rs;
    const TI* inS = in + (size_t)slice * (N_ * 32);
    int cnt = ell_cnt[row];
    const int* cols = ell_col + row * ELLW;
    const float* vals = ell_val + row * ELLW;
    float a0 = 0.f, a1 = 0.f;
    for (int i = 0; i < cnt; i += 8) {
        int4 c0 = *(const int4*)(cols + i);
        int4 c1 = *(const int4*)(cols + i + 4);
        float4 v0 = *(const float4*)(vals + i);
        float4 v1 = *(const float4*)(vals + i + 4);
        float x0, y0, x1, y1, x2, y2, x3, y3, x4, y4, x5, y5, x6, y6, x7, y7;
        ld2(inS + c0.x * 32 + 2 * dp, x0, y0);
        ld2(inS + c0.y * 32 + 2 * dp, x1, y1);
        ld2(inS + c0.z * 32 + 2 * dp, x2, y2);
        ld2(inS + c0.w * 32 + 2 * dp, x3, y3);
        ld2(inS + c1.x * 32 + 2 * dp, x4, y4);
        ld2(inS + c1.y * 32 + 2 * dp, x5, y5);
        ld2(inS + c1.z * 32 + 2 * dp, x6, y6);
        ld2(inS + c1.w * 32 + 2 * dp, x7, y7);
        a0 += v0.x * x0; a1 += v0.x * y0;
        a0 += v0.y * x1; a1 += v0.y * y1;
        a0 += v0.z * x2; a1 += v0.z * y2;
        a0 += v0.w * x3; a1 += v0.w * y3;
        a0 += v1.x * x4; a1 += v1.x * y4;
        a0 += v1.y * x5; a1 += v1.y * y5;
        a0 += v1.z * x6; a1 += v1.z * y6;
        a0 += v1.w * x7; a1 += v1.w * y7;
    }
    size_t idx = (size_t)slice * (N_ * 32) + (size_t)row * 32 + 2 * dp;
    float t0, t1;
    if (prevb) {
        float p0, p1; ld2(prevb + idx, p0, p1);
        t0 = 2.f * a0 - p0; t1 = 2.f * a1 - p1;
    } else { t0 = a0; t1 = a1; }
    *(unsigned int*)(out + idx) = pk2(t0, t1);
}

// ---------------------------------------------------------------- step 0: H = (1 - sigmoid(GX0_u)) * tanh(CX0)   (h0 == 0 exactly)
__global__ __launch_bounds__(256) void k_step0(const float* __restrict__ GX, const float* __restrict__ CX,
                                               float* __restrict__ H) {
    int gid = blockIdx.x * 256 + threadIdx.x;
    int d = gid & 31, g = gid >> 5;
    float uv = 1.f / (1.f + expf(-GX[(size_t)g * 64 + 32 + d]));
    float c = tanhf(CX[(size_t)g * 32 + d]);
    H[(size_t)g * 32 + d] = (1.f - uv) * c;
}

// ---------------------------------------------------------------- gate: 512 blocks, 16 rows; d-pair gathers + GEMM + sigmoid
__global__ __launch_bounds__(256) void k_gate(const float* __restrict__ H, const bf16* __restrict__ HC1,
                                              const bf16* __restrict__ HC2, const float* __restrict__ GXt,
                                              const float* __restrict__ wgh,
                                              const float* __restrict__ ell_val, const int* __restrict__ ell_col,
                                              const int* __restrict__ ell_cnt,
                                              bf16* __restrict__ U, bf16* __restrict__ RH) {
    __shared__ float wg[8192];
    __shared__ float st[128][18];
    int tid = threadIdx.x;
    {
        const float4* src = (const float4*)wgh;
        float4* dst = (float4*)wg;
        #pragma unroll
        for (int i = 0; i < 8; ++i) dst[tid + i * 256] = src[tid + i * 256];
    }
    int dp = tid & 15, rs = tid >> 4;        // 16 rows/block, d-pair per thread
    int b = blockIdx.x & 3;
    int rb = blockIdx.x >> 2;
    const bf16* H2s = HC2 + (size_t)b * (N_ * 32);
    {
        int n = rb * 16 + rs;
        size_t idx = ((size_t)b * N_ + n) * 32 + 2 * dp;
        float hv0, hv1, h1a, h1b, h2a, h2b;
        ld2(H + idx, hv0, hv1);
        ld2(HC1 + idx, h1a, h1b);
        ld2(HC2 + idx, h2a, h2b);
        int cnt = ell_cnt[n];
        const int* cols = ell_col + n * ELLW;
        const float* vals = ell_val + n * ELLW;
        float a0 = 0.f, a1 = 0.f;
        for (int j = 0; j < cnt; j += 8) {
            int4 c0 = *(const int4*)(cols + j);
            int4 c1 = *(const int4*)(cols + j + 4);
            float4 v0 = *(const float4*)(vals + j);
            float4 v1 = *(const float4*)(vals + j + 4);
            unsigned int u0 = *(const unsigned int*)(H2s + c0.x * 32 + 2 * dp);
            unsigned int u1 = *(const unsigned int*)(H2s + c0.y * 32 + 2 * dp);
            unsigned int u2 = *(const unsigned int*)(H2s + c0.z * 32 + 2 * dp);
            unsigned int u3 = *(const unsigned int*)(H2s + c0.w * 32 + 2 * dp);
            unsigned int u4 = *(const unsigned int*)(H2s + c1.x * 32 + 2 * dp);
            unsigned int u5 = *(const unsigned int*)(H2s + c1.y * 32 + 2 * dp);
            unsigned int u6 = *(const unsigned int*)(H2s + c1.z * 32 + 2 * dp);
            unsigned int u7 = *(const unsigned int*)(H2s + c1.w * 32 + 2 * dp);
            a0 += v0.x * bflo(u0); a1 += v0.x * bfhi(u0);
            a0 += v0.y * bflo(u1); a1 += v0.y * bfhi(u1);
            a0 += v0.z * bflo(u2); a1 += v0.z * bfhi(u2);
            a0 += v0.w * bflo(u3); a1 += v0.w * bfhi(u3);
            a0 += v1.x * bflo(u4); a1 += v1.x * bfhi(u4);
            a0 += v1.y * bflo(u5); a1 += v1.y * bfhi(u5);
            a0 += v1.z * bflo(u6); a1 += v1.z * bfhi(u6);
            a0 += v1.w * bflo(u7); a1 += v1.w * bfhi(u7);
        }
        st[2 * dp][rs] = hv0;       st[2 * dp + 1][rs] = hv1;
        st[32 + 2 * dp][rs] = h1a;  st[32 + 2 * dp + 1][rs] = h1b;
        st[64 + 2 * dp][rs] = h2a;  st[64 + 2 * dp + 1][rs] = h2b;
        st[96 + 2 * dp][rs] = 2.f * a0 - h1a;
        st[96 + 2 * dp + 1][rs] = 2.f * a1 - h1b;
    }
    __syncthreads();
    int d = tid & 31, rg = tid >> 5;
    int n0 = rb * 16 + rg * 2;
    float a0[2], a1[2];
    #pragma unroll
    for (int i = 0; i < 2; ++i) {
        size_t g = (size_t)b * N_ + n0 + i;
        a0[i] = GXt[g * 64 + d];
        a1[i] = GXt[g * 64 + 32 + d];
    }
    #pragma unroll 4
    for (int kk = 0; kk < 128; ++kk) {
        float2 v = *(const float2*)&st[kk][rg * 2];
        float u0 = wg[kk * 64 + d], u1 = wg[kk * 64 + 32 + d];
        a0[0] += v.x * u0; a0[1] += v.y * u0;
        a1[0] += v.x * u1; a1[1] += v.y * u1;
    }
    #pragma unroll
    for (int i = 0; i < 2; ++i) {
        float rv = 1.f / (1.f + expf(-a0[i]));
        float uv = 1.f / (1.f + expf(-a1[i]));
        float hv = st[d][rg * 2 + i];
        size_t idx = ((size_t)b * N_ + n0 + i) * 32 + d;
        U[idx] = __float2bfloat16(uv);
        RH[idx] = __float2bfloat16(rv * hv);
    }
}

// ---------------------------------------------------------------- cand: 512 blocks, 16 rows; d-pair gathers + GEMM + tanh + update
__global__ __launch_bounds__(256) void k_cand(const bf16* __restrict__ RHv, const bf16* __restrict__ RC1,
                                              const bf16* __restrict__ RC2, const float* __restrict__ CXt,
                                              const float* __restrict__ wch,
                                              const float* __restrict__ ell_val, const int* __restrict__ ell_col,
                                              const int* __restrict__ ell_cnt,
                                              const bf16* __restrict__ U, float* __restrict__ H) {
    __shared__ float wc[4096];
    __shared__ float st[128][18];
    int tid = threadIdx.x;
    {
        const float4* src = (const float4*)wch;
        float4* dst = (float4*)wc;
        #pragma unroll
        for (int i = 0; i < 4; ++i) dst[tid + i * 256] = src[tid + i * 256];
    }
    int dp = tid & 15, rs = tid >> 4;
    int b = blockIdx.x & 3;
    int rb = blockIdx.x >> 2;
    const bf16* R2s = RC2 + (size_t)b * (N_ * 32);
    {
        int n = rb * 16 + rs;
        size_t idx = ((size_t)b * N_ + n) * 32 + 2 * dp;
        float rh0, rh1, r1a, r1b, r2a, r2b;
        ld2(RHv + idx, rh0, rh1);
        ld2(RC1 + idx, r1a, r1b);
        ld2(RC2 + idx, r2a, r2b);
        int cnt = ell_cnt[n];
        const int* cols = ell_col + n * ELLW;
        const float* vals = ell_val + n * ELLW;
        float a0 = 0.f, a1 = 0.f;
        for (int j = 0; j < cnt; j += 8) {
            int4 c0 = *(const int4*)(cols + j);
            int4 c1 = *(const int4*)(cols + j + 4);
            float4 v0 = *(const float4*)(vals + j);
            float4 v1 = *(const float4*)(vals + j + 4);
            unsigned int u0 = *(const unsigned int*)(R2s + c0.x * 32 + 2 * dp);
            unsigned int u1 = *(const unsigned int*)(R2s + c0.y * 32 + 2 * dp);
            unsigned int u2 = *(const unsigned int*)(R2s + c0.z * 32 + 2 * dp);
            unsigned int u3 = *(const unsigned int*)(R2s + c0.w * 32 + 2 * dp);
            unsigned int u4 = *(const unsigned int*)(R2s + c1.x * 32 + 2 * dp);
            unsigned int u5 = *(const unsigned int*)(R2s + c1.y * 32 + 2 * dp);
            unsigned int u6 = *(const unsigned int*)(R2s + c1.z * 32 + 2 * dp);
            unsigned int u7 = *(const unsigned int*)(R2s + c1.w * 32 + 2 * dp);
            a0 += v0.x * bflo(u0); a1 += v0.x * bfhi(u0);
            a0 += v0.y * bflo(u1); a1 += v0.y * bfhi(u1);
            a0 += v0.z * bflo(u2); a1 += v0.z * bfhi(u2);
            a0 += v0.w * bflo(u3); a1 += v0.w * bfhi(u3);
            a0 += v1.x * bflo(u4); a1 += v1.x * bfhi(u4);
            a0 += v1.y * bflo(u5); a1 += v1.y * bfhi(u5);
            a0 += v1.z * bflo(u6); a1 += v1.z * bfhi(u6);
            a0 += v1.w * bflo(u7); a1 += v1.w * bfhi(u7);
        }
        st[2 * dp][rs] = rh0;       st[2 * dp + 1][rs] = rh1;
        st[32 + 2 * dp][rs] = r1a;  st[32 + 2 * dp + 1][rs] = r1b;
        st[64 + 2 * dp][rs] = r2a;  st[64 + 2 * dp + 1][rs] = r2b;
        st[96 + 2 * dp][rs] = 2.f * a0 - r1a;
        st[96 + 2 * dp + 1][rs] = 2.f * a1 - r1b;
    }
    __syncthreads();
    int d = tid & 31, rg = tid >> 5;
    int n0 = rb * 16 + rg * 2;
    float ac[2];
    #pragma unroll
    for (int i = 0; i < 2; ++i) ac[i] = CXt[((size_t)b * N_ + n0 + i) * 32 + d];
    #pragma unroll 4
    for (int kk = 0; kk < 128; ++kk) {
        float2 v = *(const float2*)&st[kk][rg * 2];
        float uc = wc[kk * 32 + d];
        ac[0] += v.x * uc; ac[1] += v.y * uc;
    }
    #pragma unroll
    for (int i = 0; i < 2; ++i) {
        float c = tanhf(ac[i]);
        size_t idx = ((size_t)b * N_ + n0 + i) * 32 + d;
        float uv = tf(U[idx]);
        float hv = H[idx];
        H[idx] = uv * hv + (1.f - uv) * c;
    }
}

// ---------------------------------------------------------------- output head
__global__ __launch_bounds__(256) void k_out(const float* __restrict__ H, const void* W1, const void* B1,
                                             const void* W2, const void* B2, const int* flagp,
                                             void* __restrict__ out) {
    __shared__ float w1[1024], w2[384], c1[32], c2[12];
    int flag = *flagp;
    int tid = threadIdx.x;
    for (int i = tid; i < 1024; i += 256) w1[i] = ld(W1, i, flag);
    for (int i = tid; i < 384; i += 256) w2[i] = ld(W2, i, flag);
    if (tid < 32) c1[tid] = ld(B1, tid, flag);
    if (tid < 12) c2[tid] = ld(B2, tid, flag);
    __syncthreads();
    int gid = blockIdx.x * 256 + tid;
    int b = gid / N_, n = gid % N_;
    float hrow[32];
    #pragma unroll
    for (int i = 0; i < 32; ++i) hrow[i] = H[(size_t)(b * N_ + n) * 32 + i];
    float hid[32];
    #pragma unroll
    for (int j = 0; j < 32; ++j) {
        float a = c1[j];
        #pragma unroll
        for (int i = 0; i < 32; ++i) a += hrow[i] * w1[i * 32 + j];
        hid[j] = fmaxf(a, 0.f);
    }
    for (int q = 0; q < 12; ++q) {
        float a = c2[q];
        #pragma unroll
        for (int j = 0; j < 32; ++j) a += hid[j] * w2[j * 12 + q];
        size_t idx = ((size_t)b * Q_ + q) * N_ + n;
        if (flag) ((float*)out)[idx] = a;
        else ((bf16*)out)[idx] = __float2bfloat16(a);
    }
}

extern "C" void kernel_launch(void* const* d_in, const int* in_sizes, int n_in,
                              void* d_out, int out_size, void* d_ws, size_t ws_size,
                              hipStream_t stream) {
    const void* X      = d_in[0];
    const int*  TE     = (const int*)d_in[1];
    const void* L      = d_in[2];
    const void* SEi    = d_in[3];
    const void* W_se1  = d_in[4];
    const void* b_se1  = d_in[5];
    const void* W_se2  = d_in[6];
    const void* b_se2  = d_in[7];
    const void* W_te1  = d_in[8];
    const void* b_te1  = d_in[9];
    const void* W_te2  = d_in[10];
    const void* b_te2  = d_in[11];
    const void* W_in1  = d_in[12];
    const void* b_in1  = d_in[13];
    const void* W_in2  = d_in[14];
    const void* b_in2  = d_in[15];
    const void* W_gate = d_in[16];
    const void* b_gate = d_in[17];
    const void* W_cand = d_in[18];
    const void* b_cand = d_in[19];
    const void* W_out1 = d_in[20];
    const void* b_out1 = d_in[21];
    const void* W_out2 = d_in[22];
    const void* b_out2 = d_in[23];

    // ---- workspace layout (fp32 units; bf16 arrays reserve elems/2) ----
    float* ws = (float*)d_ws;
    size_t o = 0;
    int*   flagp   = (int*)(ws + o); o += 16;
    float* ell_val = ws + o; o += (size_t)N_ * ELLW;
    int*   ell_col = (int*)(ws + o); o += (size_t)N_ * ELLW;
    int*   ell_cnt = (int*)(ws + o); o += N_;
    float* se = ws + o; o += (size_t)N_ * 32;
    float* te = ws + o; o += (size_t)B_ * P_ * 32;
    float* wgh = ws + o; o += 8192;
    float* wch = ws + o; o += 4096;
    const size_t TSZ = (size_t)P_ * B_ * N_ * 32;       // elems
    bf16* Ta = (bf16*)(ws + o); o += TSZ / 2;           // T0, later T2 (in place)
    bf16* Tb = (bf16*)(ws + o); o += TSZ / 2;           // T1
    float* GX = ws + o; o += (size_t)P_ * B_ * N_ * 64; // fp32 (4x RMW accumulation)
    float* CX = ws + o; o += TSZ;                       // fp32
    const size_t HSZ = (size_t)B_ * N_ * 32;            // elems
    float* H   = ws + o; o += HSZ;                      // fp32 recurrent state
    bf16* HC1 = (bf16*)(ws + o); o += HSZ / 2;
    bf16* HC2 = (bf16*)(ws + o); o += HSZ / 2;
    bf16* RH  = (bf16*)(ws + o); o += HSZ / 2;
    bf16* RC1 = (bf16*)(ws + o); o += HSZ / 2;
    bf16* RC2 = (bf16*)(ws + o); o += HSZ / 2;
    bf16* Ub  = (bf16*)(ws + o); o += HSZ / 2;

    k_detect<<<1, 256, 0, stream>>>(L, flagp);
    k_build_ell<<<N_, 256, 0, stream>>>(L, flagp, ell_val, ell_col, ell_cnt);
    k_prepw<<<32, 256, 0, stream>>>(W_gate, W_cand, flagp, wgh, wch);
    k_se<<<N_ / 8, 256, 0, stream>>>(SEi, W_se1, b_se1, W_se2, b_se2, flagp, se);
    k_te<<<(B_ * P_) / 8, 256, 0, stream>>>(TE, W_te1, b_te1, W_te2, b_te2, flagp, te);

    // x-side Chebyshev + fold (once, batched over all t,b)
    const int GBIG = P_ * B_ * N_ / 32;     // 3072
    k_xt_fold<<<GBIG, 256, 0, stream>>>(X, W_in1, b_in1, W_in2, b_in2, W_gate, b_gate, W_cand, b_cand,
                                        se, te, flagp, Ta, GX, CX);
    k_hop_fold<<<GBIG, 256, 0, stream>>>(1, Ta, nullptr, Tb, W_gate, W_cand,
                                         ell_val, ell_col, ell_cnt, flagp, GX, CX);
    k_hop_fold<<<GBIG, 256, 0, stream>>>(2, Tb, Ta, Ta, W_gate, W_cand,
                                         ell_val, ell_col, ell_cnt, flagp, GX, CX);
    k_hop_fold<<<GBIG, 256, 0, stream>>>(3, Ta, Tb, nullptr, W_gate, W_cand,
                                         ell_val, ell_col, ell_cnt, flagp, GX, CX);

    // t = 0: H starts at exactly zero -> single elementwise step
    k_step0<<<(B_ * N_ * 32) / 256, 256, 0, stream>>>(GX, CX, H);

    for (int t = 1; t < P_; ++t) {
        const float* GXt = GX + (size_t)t * B_ * N_ * 64;
        const float* CXt = CX + (size_t)t * B_ * N_ * 32;
        k_spmm1<float, float><<<B_ * N_ / 16, 256, 0, stream>>>(H, (const float*)nullptr, HC1,
                                                                ell_val, ell_col, ell_cnt);
        k_spmm1<bf16, float><<<B_ * N_ / 16, 256, 0, stream>>>(HC1, H, HC2,
                                                               ell_val, ell_col, ell_cnt);
        k_gate<<<B_ * N_ / 16, 256, 0, stream>>>(H, HC1, HC2, GXt, wgh,
                                                 ell_val, ell_col, ell_cnt, Ub, RH);
        k_spmm1<bf16, float><<<B_ * N_ / 16, 256, 0, stream>>>(RH, (const float*)nullptr, RC1,
                                                               ell_val, ell_col, ell_cnt);
        k_spmm1<bf16, bf16><<<B_ * N_ / 16, 256, 0, stream>>>(RC1, RH, RC2,
                                                              ell_val, ell_col, ell_cnt);
        k_cand<<<B_ * N_ / 16, 256, 0, stream>>>(RH, RC1, RC2, CXt, wch,
                                                 ell_val, ell_col, ell_cnt, Ub, H);
    }
    k_out<<<B_ * N_ / 256, 256, 0, stream>>>(H, W_out1, b_out1, W_out2, b_out2, flagp, (void*)d_out);
}

// Round 13
// 729.726 us; speedup vs baseline: 1.0601x; 1.0055x over previous
//
#include <hip/hip_runtime.h>
#include <hip/hip_bf16.h>

#define B_ 4
#define P_ 12
#define Q_ 12
#define N_ 2048
#define D_ 32
#define ELLW 96

typedef __hip_bfloat16 bf16;

// Dual-path input load: flag==0 -> bf16 storage, flag==1 -> fp32 storage.
__device__ __forceinline__ float ld(const void* p, int i, int flag) {
    if (flag) return ((const float*)p)[i];
    unsigned int u = ((const unsigned short*)p)[i];
    return __uint_as_float(u << 16);
}

__device__ __forceinline__ float tf(float x) { return x; }
__device__ __forceinline__ float tf(bf16 x) { return __bfloat162float(x); }
__device__ __forceinline__ float bflo(unsigned int u) { return __uint_as_float(u << 16); }
__device__ __forceinline__ float bfhi(unsigned int u) { return __uint_as_float(u & 0xffff0000u); }
__device__ __forceinline__ unsigned int pk2(float a, float b) {
    bf16 x = __float2bfloat16(a), y = __float2bfloat16(b);
    unsigned short lo = *(unsigned short*)&x, hi = *(unsigned short*)&y;
    return (unsigned int)lo | ((unsigned int)hi << 16);
}
// packed pair load: bf16 source -> dword, float source -> float2
__device__ __forceinline__ void ld2(const bf16* p, float& a, float& b) {
    unsigned int u = *(const unsigned int*)p; a = bflo(u); b = bfhi(u);
}
__device__ __forceinline__ void ld2(const float* p, float& a, float& b) {
    float2 v = *(const float2*)p; a = v.x; b = v.y;
}
// 4-element bf16 load/store (dwordx2)
__device__ __forceinline__ void ld4b(const bf16* p, float4& v) {
    uint2 u = *(const uint2*)p;
    v.x = bflo(u.x); v.y = bfhi(u.x); v.z = bflo(u.y); v.w = bfhi(u.y);
}
__device__ __forceinline__ void st4b(bf16* p, float4 v) {
    uint2 o; o.x = pk2(v.x, v.y); o.y = pk2(v.z, v.w);
    *(uint2*)p = o;
}

// ------------------------------------------------------------ dtype detector
__global__ void k_detect(const void* L, int* flagp) {
    __shared__ int c;
    if (threadIdx.x == 0) c = 0;
    __syncthreads();
    const unsigned short* p = (const unsigned short*)L;
    int bad = 0;
    for (int i = threadIdx.x; i < 8192; i += 256) {
        unsigned int u = p[i];
        float v = __uint_as_float(u << 16);
        if (isnan(v) || isinf(v) || (v != 0.f && (fabsf(v) < 1e-8f || fabsf(v) > 1e4f))) bad = 1;
    }
    atomicOr(&c, bad);
    __syncthreads();
    if (threadIdx.x == 0) *flagp = (c != 0) ? 1 : 0;
}

// ---------------------------------------------------------------- ELL build (rows padded to x8 with zeros)
__global__ __launch_bounds__(256) void k_build_ell(const void* L, const int* flagp,
                                                   float* __restrict__ ell_val,
                                                   int* __restrict__ ell_col,
                                                   int* __restrict__ ell_cnt) {
    int flag = *flagp;
    int row = blockIdx.x;
    __shared__ int cnt;
    if (threadIdx.x == 0) cnt = 0;
    __syncthreads();
    for (int c = threadIdx.x; c < N_; c += 256) {
        float v = ld(L, row * N_ + c, flag);
        if (v != 0.0f) {
            int s = atomicAdd(&cnt, 1);
            if (s < ELLW) { ell_col[row * ELLW + s] = c; ell_val[row * ELLW + s] = v; }
        }
    }
    __syncthreads();
    int c = cnt < ELLW ? cnt : ELLW;
    int c8 = (c + 7) & ~7;
    for (int s = c + threadIdx.x; s < c8; s += 256) { ell_col[row * ELLW + s] = 0; ell_val[row * ELLW + s] = 0.f; }
    if (threadIdx.x == 0) ell_cnt[row] = c8;
}

// ---------------------------------------------------------------- fp32 copies of h-half weights (layout = LDS layout)
__global__ __launch_bounds__(256) void k_prepw(const void* W_gate, const void* W_cand, const int* flagp,
                                               float* __restrict__ wgh, float* __restrict__ wch) {
    int flag = *flagp;
    int tid = blockIdx.x * 256 + threadIdx.x;
    if (tid < 8192) {
        int kk = tid >> 6, c = tid & 63;
        wgh[tid] = ld(W_gate, ((kk >> 5) * 64 + 32 + (kk & 31)) * 64 + c, flag);
    }
    if (tid < 4096) {
        int kk = tid >> 5, c = tid & 31;
        wch[tid] = ld(W_cand, ((kk >> 5) * 64 + 32 + (kk & 31)) * 32 + c, flag);
    }
}

// ---------------------------------------------------------------- se = relu(SE@W1+b1)@W2+b2
__global__ __launch_bounds__(256) void k_se(const void* SE, const void* W1, const void* B1,
                                            const void* W2, const void* B2, const int* flagp,
                                            float* __restrict__ se) {
    __shared__ float w1[1024], w2[1024], c1[32], c2[32];
    __shared__ float srow[8][33], hid[8][33];
    int flag = *flagp;
    int tid = threadIdx.x;
    for (int i = tid; i < 1024; i += 256) { w1[i] = ld(W1, i, flag); w2[i] = ld(W2, i, flag); }
    if (tid < 32) { c1[tid] = ld(B1, tid, flag); c2[tid] = ld(B2, tid, flag); }
    int r = tid >> 5, d = tid & 31;
    int row = blockIdx.x * 8 + r;
    srow[r][d] = ld(SE, row * 32 + d, flag);
    __syncthreads();
    float a = c1[d];
    #pragma unroll
    for (int i = 0; i < 32; ++i) a += srow[r][i] * w1[i * 32 + d];
    hid[r][d] = fmaxf(a, 0.f);
    __syncthreads();
    float o = c2[d];
    #pragma unroll
    for (int i = 0; i < 32; ++i) o += hid[r][i] * w2[i * 32 + d];
    se[row * 32 + d] = o;
}

// ---------------------------------------------------------------- te
__global__ __launch_bounds__(256) void k_te(const int* __restrict__ TE, const void* W1, const void* B1,
                                            const void* W2, const void* B2, const int* flagp,
                                            float* __restrict__ te) {
    __shared__ float w2[1024], c1[32], c2[32];
    __shared__ float hid[8][33];
    int flag = *flagp;
    int tid = threadIdx.x;
    for (int i = tid; i < 1024; i += 256) w2[i] = ld(W2, i, flag);
    if (tid < 32) { c1[tid] = ld(B1, tid, flag); c2[tid] = ld(B2, tid, flag); }
    __syncthreads();
    int r = tid >> 5, d = tid & 31;
    int row = blockIdx.x * 8 + r;   // row = b*P + t
    int b = row / P_, t = row % P_;
    int day = TE[(b * (P_ + Q_) + t) * 2 + 0];
    int tod = TE[(b * (P_ + Q_) + t) * 2 + 1];
    float a = ld(W1, day * 32 + d, flag) + ld(W1, (7 + tod) * 32 + d, flag) + c1[d];
    hid[r][d] = fmaxf(a, 0.f);
    __syncthreads();
    float o = c2[d];
    #pragma unroll
    for (int i = 0; i < 32; ++i) o += hid[r][i] * w2[i * 32 + d];
    te[row * 32 + d] = o;
}

// ---------------------------------------------------------------- xt for all (t,b): T0 (bf16) + fold order-0 into GX/CX (fp32, init w/ bias)
__global__ __launch_bounds__(256) void k_xt_fold(const void* X, const void* W_in1, const void* b_in1,
        const void* W_in2, const void* b_in2, const void* W_gate, const void* b_gate,
        const void* W_cand, const void* b_cand,
        const float* __restrict__ se, const float* __restrict__ te, const int* flagp,
        bf16* __restrict__ T0, float* __restrict__ GX, float* __restrict__ CX) {
    __shared__ float w2[1024], wg0[2048], wc0[1024];
    __shared__ float w1s[32], c1s[32], c2s[32];
    __shared__ float hid[32][33];
    __shared__ float st[32][36];   // [feat][row]
    int flag = *flagp;
    int tid = threadIdx.x;
    for (int i = tid; i < 1024; i += 256) w2[i] = ld(W_in2, i, flag);
    for (int i = tid; i < 2048; i += 256) { int j = i >> 6, c = i & 63; wg0[i] = ld(W_gate, j * 64 + c, flag); }
    for (int i = tid; i < 1024; i += 256) { int j = i >> 5, c = i & 31; wc0[i] = ld(W_cand, j * 32 + c, flag); }
    if (tid < 32) { w1s[tid] = ld(W_in1, tid, flag); c1s[tid] = ld(b_in1, tid, flag); c2s[tid] = ld(b_in2, tid, flag); }
    __syncthreads();
    int sr = tid >> 5, d = tid & 31;
    int g0 = blockIdx.x * 32;
    #pragma unroll
    for (int rr = 0; rr < 4; ++rr) {
        int lrow = sr * 4 + rr;
        int g = g0 + lrow;
        int t = g / (B_ * N_); int rem = g - t * B_ * N_; int b = rem >> 11; int n = rem & (N_ - 1);
        float xv = ld(X, (b * P_ + t) * N_ + n, flag);
        hid[lrow][d] = fmaxf(xv * w1s[d] + c1s[d], 0.f);
    }
    __syncthreads();
    #pragma unroll
    for (int rr = 0; rr < 4; ++rr) {
        int lrow = sr * 4 + rr;
        int g = g0 + lrow;
        int t = g / (B_ * N_); int rem = g - t * B_ * N_; int b = rem >> 11; int n = rem & (N_ - 1);
        float o = c2s[d] + se[n * 32 + d] + te[(b * P_ + t) * 32 + d];
        #pragma unroll
        for (int i = 0; i < 32; ++i) o += hid[lrow][i] * w2[i * 32 + d];
        T0[(size_t)g * 32 + d] = __float2bfloat16(o);
        st[d][lrow] = o;
    }
    __syncthreads();
    int d0 = tid & 31, rg = tid >> 5;   // rows rg*4..+3
    float a0[4], a1[4], ac[4];
    float bg0 = ld(b_gate, d0, flag), bg1 = ld(b_gate, 32 + d0, flag), bcv = ld(b_cand, d0, flag);
    #pragma unroll
    for (int i = 0; i < 4; ++i) { a0[i] = bg0; a1[i] = bg1; ac[i] = bcv; }
    #pragma unroll 4
    for (int j = 0; j < 32; ++j) {
        float4 v = *(const float4*)&st[j][rg * 4];
        float u0 = wg0[j * 64 + d0], u1 = wg0[j * 64 + 32 + d0], uc = wc0[j * 32 + d0];
        a0[0] += v.x * u0; a0[1] += v.y * u0; a0[2] += v.z * u0; a0[3] += v.w * u0;
        a1[0] += v.x * u1; a1[1] += v.y * u1; a1[2] += v.z * u1; a1[3] += v.w * u1;
        ac[0] += v.x * uc; ac[1] += v.y * uc; ac[2] += v.z * uc; ac[3] += v.w * uc;
    }
    #pragma unroll
    for (int i = 0; i < 4; ++i) {
        int g = g0 + rg * 4 + i;
        GX[(size_t)g * 64 + d0] = a0[i];
        GX[(size_t)g * 64 + 32 + d0] = a1[i];
        CX[(size_t)g * 32 + d0] = ac[i];
    }
}

// ---------------------------------------------------------------- Chebyshev hop over 48 slices (bf16, d-quad gathers)
// + fused fold order-k (fp32 RMW GX/CX). XCD swizzle: slice = blockIdx % 48
__global__ __launch_bounds__(256) void k_hop_fold(int k, const bf16* __restrict__ in, const bf16* __restrict__ prevb,
        bf16* __restrict__ outT, const void* W_gate, const void* W_cand,
        const float* __restrict__ ell_val, const int* __restrict__ ell_col, const int* __restrict__ ell_cnt,
        const int* flagp, float* __restrict__ GX, float* __restrict__ CX) {
    __shared__ float wgk[2048], wck[1024];
    __shared__ float st[32][36];
    int flag = *flagp;
    int tid = threadIdx.x;
    for (int i = tid; i < 2048; i += 256) { int j = i >> 6, c = i & 63; wgk[i] = ld(W_gate, (k * 64 + j) * 64 + c, flag); }
    for (int i = tid; i < 1024; i += 256) { int j = i >> 5, c = i & 31; wck[i] = ld(W_cand, (k * 64 + j) * 32 + c, flag); }
    int dq = tid & 7, rl = tid >> 3;
    int d0 = dq * 4;
    int slice = blockIdx.x % 48;
    int rb = blockIdx.x / 48;
    const bf16* inS = in + (size_t)slice * (N_ * 32);
    // NOTE: no barrier here — wgk/wck are only read after the barrier below;
    // the gather section touches a disjoint LDS array (st). Removing the
    // redundant barrier lets the gather start without draining staging loads.
    {
        int row = rb * 32 + rl;
        int cnt = ell_cnt[row];
        const int* cols = ell_col + row * ELLW;
        const float* vals = ell_val + row * ELLW;
        float4 a = {0.f, 0.f, 0.f, 0.f};
        for (int i = 0; i < cnt; i += 8) {
            int4 c0 = *(const int4*)(cols + i);
            int4 c1 = *(const int4*)(cols + i + 4);
            float4 v0 = *(const float4*)(vals + i);
            float4 v1 = *(const float4*)(vals + i + 4);
            float4 x;
            ld4b(inS + c0.x * 32 + d0, x); a.x += v0.x * x.x; a.y += v0.x * x.y; a.z += v0.x * x.z; a.w += v0.x * x.w;
            ld4b(inS + c0.y * 32 + d0, x); a.x += v0.y * x.x; a.y += v0.y * x.y; a.z += v0.y * x.z; a.w += v0.y * x.w;
            ld4b(inS + c0.z * 32 + d0, x); a.x += v0.z * x.x; a.y += v0.z * x.y; a.z += v0.z * x.z; a.w += v0.z * x.w;
            ld4b(inS + c0.w * 32 + d0, x); a.x += v0.w * x.x; a.y += v0.w * x.y; a.z += v0.w * x.z; a.w += v0.w * x.w;
            ld4b(inS + c1.x * 32 + d0, x); a.x += v1.x * x.x; a.y += v1.x * x.y; a.z += v1.x * x.z; a.w += v1.x * x.w;
            ld4b(inS + c1.y * 32 + d0, x); a.x += v1.y * x.x; a.y += v1.y * x.y; a.z += v1.y * x.z; a.w += v1.y * x.w;
            ld4b(inS + c1.z * 32 + d0, x); a.x += v1.z * x.x; a.y += v1.z * x.y; a.z += v1.z * x.z; a.w += v1.z * x.w;
            ld4b(inS + c1.w * 32 + d0, x); a.x += v1.w * x.x; a.y += v1.w * x.y; a.z += v1.w * x.z; a.w += v1.w * x.w;
        }
        size_t idx = (size_t)slice * (N_ * 32) + (size_t)row * 32 + d0;
        float4 t = a;
        if (prevb) {
            float4 p; ld4b(prevb + idx, p);
            t.x = 2.f * a.x - p.x; t.y = 2.f * a.y - p.y;
            t.z = 2.f * a.z - p.z; t.w = 2.f * a.w - p.w;
        }
        if (outT) st4b(outT + idx, t);
        st[d0][rl] = t.x; st[d0 + 1][rl] = t.y; st[d0 + 2][rl] = t.z; st[d0 + 3][rl] = t.w;
    }
    __syncthreads();
    int d = tid & 31, rg = tid >> 5;
    int grow0 = slice * N_ + rb * 32 + rg * 4;
    float a0[4], a1[4], ac[4];
    #pragma unroll
    for (int i = 0; i < 4; ++i) {
        int g = grow0 + i;
        a0[i] = GX[(size_t)g * 64 + d];
        a1[i] = GX[(size_t)g * 64 + 32 + d];
        ac[i] = CX[(size_t)g * 32 + d];
    }
    #pragma unroll 4
    for (int j = 0; j < 32; ++j) {
        float4 v = *(const float4*)&st[j][rg * 4];
        float u0 = wgk[j * 64 + d], u1 = wgk[j * 64 + 32 + d], uc = wck[j * 32 + d];
        a0[0] += v.x * u0; a0[1] += v.y * u0; a0[2] += v.z * u0; a0[3] += v.w * u0;
        a1[0] += v.x * u1; a1[1] += v.y * u1; a1[2] += v.z * u1; a1[3] += v.w * u1;
        ac[0] += v.x * uc; ac[1] += v.y * uc; ac[2] += v.z * uc; ac[3] += v.w * uc;
    }
    #pragma unroll
    for (int i = 0; i < 4; ++i) {
        int g = grow0 + i;
        GX[(size_t)g * 64 + d] = a0[i];
        GX[(size_t)g * 64 + 32 + d] = a1[i];
        CX[(size_t)g * 32 + d] = ac[i];
    }
}

// ---------------------------------------------------------------- scan hop: 512 blocks = 4 slices x 128 rowblocks; d-pair gathers (8 waves/CU)
template<typename TI, typename TP>
__global__ __launch_bounds__(256) void k_spmm1(const TI* __restrict__ in, const TP* __restrict__ prevb,
                                               bf16* __restrict__ out,
                                               const float* __restrict__ ell_val, const int* __restrict__ ell_col,
                                               const int* __restrict__ ell_cnt) {
    int dp = threadIdx.x & 15, rs = threadIdx.x >> 4;   // 16 rows/block
    int slice = blockIdx.x & 3;
    int rb = blockIdx.x >> 2;
    int row = rb * 16 + rs;
    const TI* inS = in + (size_t)slice * (N_ * 32);
    int cnt = ell_cnt[row];
    const int* cols = ell_col + row * ELLW;
    const float* vals = ell_val + row * ELLW;
    float a0 = 0.f, a1 = 0.f;
    for (int i = 0; i < cnt; i += 8) {
        int4 c0 = *(const int4*)(cols + i);
        int4 c1 = *(const int4*)(cols + i + 4);
        float4 v0 = *(const float4*)(vals + i);
        float4 v1 = *(const float4*)(vals + i + 4);
        float x0, y0, x1, y1, x2, y2, x3, y3, x4, y4, x5, y5, x6, y6, x7, y7;
        ld2(inS + c0.x * 32 + 2 * dp, x0, y0);
        ld2(inS + c0.y * 32 + 2 * dp, x1, y1);
        ld2(inS + c0.z * 32 + 2 * dp, x2, y2);
        ld2(inS + c0.w * 32 + 2 * dp, x3, y3);
        ld2(inS + c1.x * 32 + 2 * dp, x4, y4);
        ld2(inS + c1.y * 32 + 2 * dp, x5, y5);
        ld2(inS + c1.z * 32 + 2 * dp, x6, y6);
        ld2(inS + c1.w * 32 + 2 * dp, x7, y7);
        a0 += v0.x * x0; a1 += v0.x * y0;
        a0 += v0.y * x1; a1 += v0.y * y1;
        a0 += v0.z * x2; a1 += v0.z * y2;
        a0 += v0.w * x3; a1 += v0.w * y3;
        a0 += v1.x * x4; a1 += v1.x * y4;
        a0 += v1.y * x5; a1 += v1.y * y5;
        a0 += v1.z * x6; a1 += v1.z * y6;
        a0 += v1.w * x7; a1 += v1.w * y7;
    }
    size_t idx = (size_t)slice * (N_ * 32) + (size_t)row * 32 + 2 * dp;
    float t0, t1;
    if (prevb) {
        float p0, p1; ld2(prevb + idx, p0, p1);
        t0 = 2.f * a0 - p0; t1 = 2.f * a1 - p1;
    } else { t0 = a0; t1 = a1; }
    *(unsigned int*)(out + idx) = pk2(t0, t1);
}

// ---------------------------------------------------------------- step 0: H = (1 - sigmoid(GX0_u)) * tanh(CX0)   (h0 == 0 exactly)
__global__ __launch_bounds__(256) void k_step0(const float* __restrict__ GX, const float* __restrict__ CX,
                                               float* __restrict__ H) {
    int gid = blockIdx.x * 256 + threadIdx.x;
    int d = gid & 31, g = gid >> 5;
    float uv = 1.f / (1.f + expf(-GX[(size_t)g * 64 + 32 + d]));
    float c = tanhf(CX[(size_t)g * 32 + d]);
    H[(size_t)g * 32 + d] = (1.f - uv) * c;
}

// ---------------------------------------------------------------- gate: 512 blocks, 16 rows; d-pair gathers + GEMM + sigmoid
__global__ __launch_bounds__(256) void k_gate(const float* __restrict__ H, const bf16* __restrict__ HC1,
                                              const bf16* __restrict__ HC2, const float* __restrict__ GXt,
                                              const float* __restrict__ wgh,
                                              const float* __restrict__ ell_val, const int* __restrict__ ell_col,
                                              const int* __restrict__ ell_cnt,
                                              bf16* __restrict__ U, bf16* __restrict__ RH) {
    __shared__ float wg[8192];
    __shared__ float st[128][18];
    int tid = threadIdx.x;
    {
        const float4* src = (const float4*)wgh;
        float4* dst = (float4*)wg;
        #pragma unroll
        for (int i = 0; i < 8; ++i) dst[tid + i * 256] = src[tid + i * 256];
    }
    int dp = tid & 15, rs = tid >> 4;        // 16 rows/block, d-pair per thread
    int b = blockIdx.x & 3;
    int rb = blockIdx.x >> 2;
    const bf16* H2s = HC2 + (size_t)b * (N_ * 32);
    {
        int n = rb * 16 + rs;
        size_t idx = ((size_t)b * N_ + n) * 32 + 2 * dp;
        float hv0, hv1, h1a, h1b, h2a, h2b;
        ld2(H + idx, hv0, hv1);
        ld2(HC1 + idx, h1a, h1b);
        ld2(HC2 + idx, h2a, h2b);
        int cnt = ell_cnt[n];
        const int* cols = ell_col + n * ELLW;
        const float* vals = ell_val + n * ELLW;
        float a0 = 0.f, a1 = 0.f;
        for (int j = 0; j < cnt; j += 8) {
            int4 c0 = *(const int4*)(cols + j);
            int4 c1 = *(const int4*)(cols + j + 4);
            float4 v0 = *(const float4*)(vals + j);
            float4 v1 = *(const float4*)(vals + j + 4);
            unsigned int u0 = *(const unsigned int*)(H2s + c0.x * 32 + 2 * dp);
            unsigned int u1 = *(const unsigned int*)(H2s + c0.y * 32 + 2 * dp);
            unsigned int u2 = *(const unsigned int*)(H2s + c0.z * 32 + 2 * dp);
            unsigned int u3 = *(const unsigned int*)(H2s + c0.w * 32 + 2 * dp);
            unsigned int u4 = *(const unsigned int*)(H2s + c1.x * 32 + 2 * dp);
            unsigned int u5 = *(const unsigned int*)(H2s + c1.y * 32 + 2 * dp);
            unsigned int u6 = *(const unsigned int*)(H2s + c1.z * 32 + 2 * dp);
            unsigned int u7 = *(const unsigned int*)(H2s + c1.w * 32 + 2 * dp);
            a0 += v0.x * bflo(u0); a1 += v0.x * bfhi(u0);
            a0 += v0.y * bflo(u1); a1 += v0.y * bfhi(u1);
            a0 += v0.z * bflo(u2); a1 += v0.z * bfhi(u2);
            a0 += v0.w * bflo(u3); a1 += v0.w * bfhi(u3);
            a0 += v1.x * bflo(u4); a1 += v1.x * bfhi(u4);
            a0 += v1.y * bflo(u5); a1 += v1.y * bfhi(u5);
            a0 += v1.z * bflo(u6); a1 += v1.z * bfhi(u6);
            a0 += v1.w * bflo(u7); a1 += v1.w * bfhi(u7);
        }
        st[2 * dp][rs] = hv0;       st[2 * dp + 1][rs] = hv1;
        st[32 + 2 * dp][rs] = h1a;  st[32 + 2 * dp + 1][rs] = h1b;
        st[64 + 2 * dp][rs] = h2a;  st[64 + 2 * dp + 1][rs] = h2b;
        st[96 + 2 * dp][rs] = 2.f * a0 - h1a;
        st[96 + 2 * dp + 1][rs] = 2.f * a1 - h1b;
    }
    __syncthreads();
    int d = tid & 31, rg = tid >> 5;
    int n0 = rb * 16 + rg * 2;
    float a0[2], a1[2];
    #pragma unroll
    for (int i = 0; i < 2; ++i) {
        size_t g = (size_t)b * N_ + n0 + i;
        a0[i] = GXt[g * 64 + d];
        a1[i] = GXt[g * 64 + 32 + d];
    }
    #pragma unroll 4
    for (int kk = 0; kk < 128; ++kk) {
        float2 v = *(const float2*)&st[kk][rg * 2];
        float u0 = wg[kk * 64 + d], u1 = wg[kk * 64 + 32 + d];
        a0[0] += v.x * u0; a0[1] += v.y * u0;
        a1[0] += v.x * u1; a1[1] += v.y * u1;
    }
    #pragma unroll
    for (int i = 0; i < 2; ++i) {
        float rv = 1.f / (1.f + expf(-a0[i]));
        float uv = 1.f / (1.f + expf(-a1[i]));
        float hv = st[d][rg * 2 + i];
        size_t idx = ((size_t)b * N_ + n0 + i) * 32 + d;
        U[idx] = __float2bfloat16(uv);
        RH[idx] = __float2bfloat16(rv * hv);
    }
}

// ---------------------------------------------------------------- cand: 512 blocks, 16 rows; d-pair gathers + GEMM + tanh + update
__global__ __launch_bounds__(256) void k_cand(const bf16* __restrict__ RHv, const bf16* __restrict__ RC1,
                                              const bf16* __restrict__ RC2, const float* __restrict__ CXt,
                                              const float* __restrict__ wch,
                                              const float* __restrict__ ell_val, const int* __restrict__ ell_col,
                                              const int* __restrict__ ell_cnt,
                                              const bf16* __restrict__ U, float* __restrict__ H) {
    __shared__ float wc[4096];
    __shared__ float st[128][18];
    int tid = threadIdx.x;
    {
        const float4* src = (const float4*)wch;
        float4* dst = (float4*)wc;
        #pragma unroll
        for (int i = 0; i < 4; ++i) dst[tid + i * 256] = src[tid + i * 256];
    }
    int dp = tid & 15, rs = tid >> 4;
    int b = blockIdx.x & 3;
    int rb = blockIdx.x >> 2;
    const bf16* R2s = RC2 + (size_t)b * (N_ * 32);
    {
        int n = rb * 16 + rs;
        size_t idx = ((size_t)b * N_ + n) * 32 + 2 * dp;
        float rh0, rh1, r1a, r1b, r2a, r2b;
        ld2(RHv + idx, rh0, rh1);
        ld2(RC1 + idx, r1a, r1b);
        ld2(RC2 + idx, r2a, r2b);
        int cnt = ell_cnt[n];
        const int* cols = ell_col + n * ELLW;
        const float* vals = ell_val + n * ELLW;
        float a0 = 0.f, a1 = 0.f;
        for (int j = 0; j < cnt; j += 8) {
            int4 c0 = *(const int4*)(cols + j);
            int4 c1 = *(const int4*)(cols + j + 4);
            float4 v0 = *(const float4*)(vals + j);
            float4 v1 = *(const float4*)(vals + j + 4);
            unsigned int u0 = *(const unsigned int*)(R2s + c0.x * 32 + 2 * dp);
            unsigned int u1 = *(const unsigned int*)(R2s + c0.y * 32 + 2 * dp);
            unsigned int u2 = *(const unsigned int*)(R2s + c0.z * 32 + 2 * dp);
            unsigned int u3 = *(const unsigned int*)(R2s + c0.w * 32 + 2 * dp);
            unsigned int u4 = *(const unsigned int*)(R2s + c1.x * 32 + 2 * dp);
            unsigned int u5 = *(const unsigned int*)(R2s + c1.y * 32 + 2 * dp);
            unsigned int u6 = *(const unsigned int*)(R2s + c1.z * 32 + 2 * dp);
            unsigned int u7 = *(const unsigned int*)(R2s + c1.w * 32 + 2 * dp);
            a0 += v0.x * bflo(u0); a1 += v0.x * bfhi(u0);
            a0 += v0.y * bflo(u1); a1 += v0.y * bfhi(u1);
            a0 += v0.z * bflo(u2); a1 += v0.z * bfhi(u2);
            a0 += v0.w * bflo(u3); a1 += v0.w * bfhi(u3);
            a0 += v1.x * bflo(u4); a1 += v1.x * bfhi(u4);
            a0 += v1.y * bflo(u5); a1 += v1.y * bfhi(u5);
            a0 += v1.z * bflo(u6); a1 += v1.z * bfhi(u6);
            a0 += v1.w * bflo(u7); a1 += v1.w * bfhi(u7);
        }
        st[2 * dp][rs] = rh0;       st[2 * dp + 1][rs] = rh1;
        st[32 + 2 * dp][rs] = r1a;  st[32 + 2 * dp + 1][rs] = r1b;
        st[64 + 2 * dp][rs] = r2a;  st[64 + 2 * dp + 1][rs] = r2b;
        st[96 + 2 * dp][rs] = 2.f * a0 - r1a;
        st[96 + 2 * dp + 1][rs] = 2.f * a1 - r1b;
    }
    __syncthreads();
    int d = tid & 31, rg = tid >> 5;
    int n0 = rb * 16 + rg * 2;
    float ac[2];
    #pragma unroll
    for (int i = 0; i < 2; ++i) ac[i] = CXt[((size_t)b * N_ + n0 + i) * 32 + d];
    #pragma unroll 4
    for (int kk = 0; kk < 128; ++kk) {
        float2 v = *(const float2*)&st[kk][rg * 2];
        float uc = wc[kk * 32 + d];
        ac[0] += v.x * uc; ac[1] += v.y * uc;
    }
    #pragma unroll
    for (int i = 0; i < 2; ++i) {
        float c = tanhf(ac[i]);
        size_t idx = ((size_t)b * N_ + n0 + i) * 32 + d;
        float uv = tf(U[idx]);
        float hv = H[idx];
        H[idx] = uv * hv + (1.f - uv) * c;
    }
}

// ---------------------------------------------------------------- output head
__global__ __launch_bounds__(256) void k_out(const float* __restrict__ H, const void* W1, const void* B1,
                                             const void* W2, const void* B2, const int* flagp,
                                             void* __restrict__ out) {
    __shared__ float w1[1024], w2[384], c1[32], c2[12];
    int flag = *flagp;
    int tid = threadIdx.x;
    for (int i = tid; i < 1024; i += 256) w1[i] = ld(W1, i, flag);
    for (int i = tid; i < 384; i += 256) w2[i] = ld(W2, i, flag);
    if (tid < 32) c1[tid] = ld(B1, tid, flag);
    if (tid < 12) c2[tid] = ld(B2, tid, flag);
    __syncthreads();
    int gid = blockIdx.x * 256 + tid;
    int b = gid / N_, n = gid % N_;
    float hrow[32];
    #pragma unroll
    for (int i = 0; i < 32; ++i) hrow[i] = H[(size_t)(b * N_ + n) * 32 + i];
    float hid[32];
    #pragma unroll
    for (int j = 0; j < 32; ++j) {
        float a = c1[j];
        #pragma unroll
        for (int i = 0; i < 32; ++i) a += hrow[i] * w1[i * 32 + j];
        hid[j] = fmaxf(a, 0.f);
    }
    for (int q = 0; q < 12; ++q) {
        float a = c2[q];
        #pragma unroll
        for (int j = 0; j < 32; ++j) a += hid[j] * w2[j * 12 + q];
        size_t idx = ((size_t)b * Q_ + q) * N_ + n;
        if (flag) ((float*)out)[idx] = a;
        else ((bf16*)out)[idx] = __float2bfloat16(a);
    }
}

extern "C" void kernel_launch(void* const* d_in, const int* in_sizes, int n_in,
                              void* d_out, int out_size, void* d_ws, size_t ws_size,
                              hipStream_t stream) {
    const void* X      = d_in[0];
    const int*  TE     = (const int*)d_in[1];
    const void* L      = d_in[2];
    const void* SEi    = d_in[3];
    const void* W_se1  = d_in[4];
    const void* b_se1  = d_in[5];
    const void* W_se2  = d_in[6];
    const void* b_se2  = d_in[7];
    const void* W_te1  = d_in[8];
    const void* b_te1  = d_in[9];
    const void* W_te2  = d_in[10];
    const void* b_te2  = d_in[11];
    const void* W_in1  = d_in[12];
    const void* b_in1  = d_in[13];
    const void* W_in2  = d_in[14];
    const void* b_in2  = d_in[15];
    const void* W_gate = d_in[16];
    const void* b_gate = d_in[17];
    const void* W_cand = d_in[18];
    const void* b_cand = d_in[19];
    const void* W_out1 = d_in[20];
    const void* b_out1 = d_in[21];
    const void* W_out2 = d_in[22];
    const void* b_out2 = d_in[23];

    // ---- workspace layout (fp32 units; bf16 arrays reserve elems/2) ----
    float* ws = (float*)d_ws;
    size_t o = 0;
    int*   flagp   = (int*)(ws + o); o += 16;
    float* ell_val = ws + o; o += (size_t)N_ * ELLW;
    int*   ell_col = (int*)(ws + o); o += (size_t)N_ * ELLW;
    int*   ell_cnt = (int*)(ws + o); o += N_;
    float* se = ws + o; o += (size_t)N_ * 32;
    float* te = ws + o; o += (size_t)B_ * P_ * 32;
    float* wgh = ws + o; o += 8192;
    float* wch = ws + o; o += 4096;
    const size_t TSZ = (size_t)P_ * B_ * N_ * 32;       // elems
    bf16* Ta = (bf16*)(ws + o); o += TSZ / 2;           // T0, later T2 (in place)
    bf16* Tb = (bf16*)(ws + o); o += TSZ / 2;           // T1
    float* GX = ws + o; o += (size_t)P_ * B_ * N_ * 64; // fp32 (4x RMW accumulation)
    float* CX = ws + o; o += TSZ;                       // fp32
    const size_t HSZ = (size_t)B_ * N_ * 32;            // elems
    float* H   = ws + o; o += HSZ;                      // fp32 recurrent state
    bf16* HC1 = (bf16*)(ws + o); o += HSZ / 2;
    bf16* HC2 = (bf16*)(ws + o); o += HSZ / 2;
    bf16* RH  = (bf16*)(ws + o); o += HSZ / 2;
    bf16* RC1 = (bf16*)(ws + o); o += HSZ / 2;
    bf16* RC2 = (bf16*)(ws + o); o += HSZ / 2;
    bf16* Ub  = (bf16*)(ws + o); o += HSZ / 2;

    k_detect<<<1, 256, 0, stream>>>(L, flagp);
    k_build_ell<<<N_, 256, 0, stream>>>(L, flagp, ell_val, ell_col, ell_cnt);
    k_prepw<<<32, 256, 0, stream>>>(W_gate, W_cand, flagp, wgh, wch);
    k_se<<<N_ / 8, 256, 0, stream>>>(SEi, W_se1, b_se1, W_se2, b_se2, flagp, se);
    k_te<<<(B_ * P_) / 8, 256, 0, stream>>>(TE, W_te1, b_te1, W_te2, b_te2, flagp, te);

    // x-side Chebyshev + fold (once, batched over all t,b)
    const int GBIG = P_ * B_ * N_ / 32;     // 3072
    k_xt_fold<<<GBIG, 256, 0, stream>>>(X, W_in1, b_in1, W_in2, b_in2, W_gate, b_gate, W_cand, b_cand,
                                        se, te, flagp, Ta, GX, CX);
    k_hop_fold<<<GBIG, 256, 0, stream>>>(1, Ta, nullptr, Tb, W_gate, W_cand,
                                         ell_val, ell_col, ell_cnt, flagp, GX, CX);
    k_hop_fold<<<GBIG, 256, 0, stream>>>(2, Tb, Ta, Ta, W_gate, W_cand,
                                         ell_val, ell_col, ell_cnt, flagp, GX, CX);
    k_hop_fold<<<GBIG, 256, 0, stream>>>(3, Ta, Tb, nullptr, W_gate, W_cand,
                                         ell_val, ell_col, ell_cnt, flagp, GX, CX);

    // t = 0: H starts at exactly zero -> single elementwise step
    k_step0<<<(B_ * N_ * 32) / 256, 256, 0, stream>>>(GX, CX, H);

    for (int t = 1; t < P_; ++t) {
        const float* GXt = GX + (size_t)t * B_ * N_ * 64;
        const float* CXt = CX + (size_t)t * B_ * N_ * 32;
        k_spmm1<float, float><<<B_ * N_ / 16, 256, 0, stream>>>(H, (const float*)nullptr, HC1,
                                                                ell_val, ell_col, ell_cnt);
        k_spmm1<bf16, float><<<B_ * N_ / 16, 256, 0, stream>>>(HC1, H, HC2,
                                                               ell_val, ell_col, ell_cnt);
        k_gate<<<B_ * N_ / 16, 256, 0, stream>>>(H, HC1, HC2, GXt, wgh,
                                                 ell_val, ell_col, ell_cnt, Ub, RH);
        k_spmm1<bf16, float><<<B_ * N_ / 16, 256, 0, stream>>>(RH, (const float*)nullptr, RC1,
                                                               ell_val, ell_col, ell_cnt);
        k_spmm1<bf16, bf16><<<B_ * N_ / 16, 256, 0, stream>>>(RC1, RH, RC2,
                                                              ell_val, ell_col, ell_cnt);
        k_cand<<<B_ * N_ / 16, 256, 0, stream>>>(RH, RC1, RC2, CXt, wch,
                                                 ell_val, ell_col, ell_cnt, Ub, H);
    }
    k_out<<<B_ * N_ / 256, 256, 0, stream>>>(H, W_out1, b_out1, W_out2, b_out2, flagp, (void*)d_out);
}